// Round 3
// baseline (1224.907 us; speedup 1.0000x reference)
//
#include <hip/hip_runtime.h>
#include <hip/hip_bf16.h>
#include <cstdint>
#include <cstddef>

using bf16 = __hip_bfloat16;
typedef __attribute__((ext_vector_type(8))) short bf16x8v;
typedef __attribute__((ext_vector_type(4))) short bf16x4v;
typedef __attribute__((ext_vector_type(4))) float f32x4v;

constexpr int Nn = 4;       // agents
constexpr int Bb = 32768;   // batch
constexpr int Ss = 512;     // state dim
constexpr int Av = 64;      // action dim
constexpr int SA = 576;     // S + A
constexpr float BN_EPS = 1e-5f;

__device__ __forceinline__ float lrelu(float v){ return v >= 0.f ? v : 0.01f * v; }
__device__ __forceinline__ float bf2f(bf16 x){ return __bfloat162float(x); }
__device__ __forceinline__ short f2bf(float v){
  union { bf16 b; short s; } u; u.b = __float2bfloat16(v); return u.s;
}

// ---------------- fused convert + BatchNorm statistics ----------------------
// Reads states/actions fp32 once (coalesced float4/lane); if WRX, writes bf16
// concat Xbf[n][b][576]; accumulates per-feature sum/sumsq.
template<bool WRX>
__global__ __launch_bounds__(256) void conv_stats(const float* __restrict__ states,
                                                  const float* __restrict__ actions,
                                                  float* __restrict__ ssum,
                                                  float* __restrict__ ssq,
                                                  short* __restrict__ Xbf){
  const int n  = blockIdx.z;
  const int tx = threadIdx.x;
  const int ty = threadIdx.y;
  const int g  = blockIdx.x * 64 + tx;   // feature group of 4
  const bool on = g < (SA / 4);
  const int f  = g * 4;
  const float* p = nullptr; int step = 0;
  if (on){
    if (f < Ss){ p = states  + (size_t)n*Bb*Ss + f;        step = Ss; }
    else       { p = actions + (size_t)n*Bb*Av + (f - Ss); step = Av; }
  }
  float s0=0.f,s1=0.f,s2=0.f,s3=0.f,q0=0.f,q1=0.f,q2=0.f,q3=0.f;
  const int b0 = blockIdx.y * 512 + ty, bend = blockIdx.y * 512 + 512;
  if (on){
    for (int b = b0; b < bend; b += 4){
      float4 v = *(const float4*)(p + (size_t)b*step);
      if (WRX){
        short t4[4] __attribute__((aligned(8))) =
            { f2bf(v.x), f2bf(v.y), f2bf(v.z), f2bf(v.w) };
        *(bf16x4v*)&Xbf[((size_t)n*Bb + b)*SA + f] = *(bf16x4v*)t4;
      }
      s0 += v.x; q0 += v.x*v.x;
      s1 += v.y; q1 += v.y*v.y;
      s2 += v.z; q2 += v.z*v.z;
      s3 += v.w; q3 += v.w*v.w;
    }
  }
  __shared__ float rs[4][64][4], rq[4][64][4];
  rs[ty][tx][0]=s0; rs[ty][tx][1]=s1; rs[ty][tx][2]=s2; rs[ty][tx][3]=s3;
  rq[ty][tx][0]=q0; rq[ty][tx][1]=q1; rq[ty][tx][2]=q2; rq[ty][tx][3]=q3;
  __syncthreads();
  if (ty == 0 && on){
    #pragma unroll
    for (int j = 0; j < 4; j++){
      float ts = rs[0][tx][j]+rs[1][tx][j]+rs[2][tx][j]+rs[3][tx][j];
      float tq = rq[0][tx][j]+rq[1][tx][j]+rq[2][tx][j]+rq[3][tx][j];
      atomicAdd(&ssum[n*SA + f + j], ts);
      atomicAdd(&ssq [n*SA + f + j], tq);
    }
  }
}

__global__ void bn_finalize(const float* __restrict__ ssum, const float* __restrict__ ssq,
                            float* __restrict__ mean, float* __restrict__ rstd){
  int i = blockIdx.x * 256 + threadIdx.x;
  float m = ssum[i] * (1.f / Bb);
  float v = ssq[i] * (1.f / Bb) - m * m;
  v = fmaxf(v, 0.f);
  mean[i] = m;
  rstd[i] = rsqrtf(v + BN_EPS);
}

// ---------------- bias pre-init: besc[a][512] = [benc | bsx] ----------------
__global__ void bias_copy(const float* __restrict__ benc, const float* __restrict__ bsx,
                          float* __restrict__ besc){
  int i = blockIdx.x * 256 + threadIdx.x;
  if (i < Nn*512){
    int a = i >> 9, c = i & 511;
    besc[i] = (c < 256) ? benc[a*256 + c] : bsx[a*256 + (c - 256)];
  }
}

// ---------------- weight prep: transpose to [col][Kd] bf16, optional fold ---
// plain (HEAD=0): dst[a*aDst + c*Kd + f] = src[a*Ks*N + f*N + c] * scale  (f<Ks, else 0)
// head  (HEAD=1): dst[c*Kd + f]          = src[(c>>4)*Ks*16 + f*16 + (c&15)]
// bias fold: bias_out[a*biasStride + c] -= sum_f mean[a*SA+f]*w'
template<int HEAD>
__global__ __launch_bounds__(256) void foldT2(const float* __restrict__ src,
                                              const float* __restrict__ scale,
                                              const float* __restrict__ mean,
                                              float* __restrict__ bias_out,
                                              short* __restrict__ dst,
                                              int Ks, int Kd, int N,
                                              int aDst, int biasStride){
  const int a  = blockIdx.z;
  const int tx = threadIdx.x & 63;
  const int ty = threadIdx.x >> 6;
  const int f0 = blockIdx.x * 64 + ty * 16;
  const int c  = blockIdx.y * 64 + tx;
  const float* s = src + (HEAD ? 0 : (size_t)a*Ks*N);
  short tmp[16] __attribute__((aligned(16)));
  float bsum = 0.f;
  #pragma unroll
  for (int j = 0; j < 16; j++){
    const int f = f0 + j;
    float w = 0.f;
    if (f < Ks){
      w = HEAD ? s[(((size_t)(c >> 4))*Ks + f)*16 + (c & 15)]
               : s[(size_t)f*N + c];
      if (scale) w *= scale[a*SA + f];
      if (mean)  bsum += mean[a*SA + f] * w;
    }
    tmp[j] = f2bf(w);
  }
  short* d = dst + (size_t)a*aDst + (size_t)c*Kd + f0;
  *(bf16x8v*)d       = *(bf16x8v*)tmp;
  *(bf16x8v*)(d + 8) = *(bf16x8v*)(tmp + 8);
  if (mean){
    __shared__ float red[4][64];
    red[ty][tx] = bsum;
    __syncthreads();
    if (threadIdx.x < 64){
      float t = red[0][threadIdx.x] + red[1][threadIdx.x]
              + red[2][threadIdx.x] + red[3][threadIdx.x];
      atomicAdd(&bias_out[a*biasStride + blockIdx.y*64 + threadIdx.x], -t);
    }
  }
}

// ---------------- MFMA GEMM -------------------------------------------------
// C[a*Bb+row][col] = act( A[row][0..K) @ W'[col][0..K)^T + bias )
// W' layout: [col][K] bf16 (k-contiguous), per-agent stride wPerAgent elems.
// ASRC: 2 bf16 pitch AP; 3 bf16 concat A1(pitch AP)|A2(pitch 256), split at 256.
// MODE: 0 normal (bias[a*biasStride+gc], ACT); 1 kv-split: gc<256 raw,
//       gc>=256 -> + bias[gc-256], lrelu.
// Tiles: BM x BN, 256 threads = 4 waves as WM x WN grid, 16x16x32 mfma frags.
template<int BM,int BN,int WM,int WN,int K,int ASRC,int AP,bool ACT,bool OUTF32,int MODE>
__global__ __launch_bounds__(256) void mgemm(const void* A1, const void* A2,
                                             const short* __restrict__ Wp, int wPerAgent,
                                             const float* __restrict__ bias, int biasStride,
                                             void* Out, int outPitch){
  __shared__ __align__(16) short As[BM*40];
  __shared__ __align__(16) short Bs[BN*40];
  const int tid  = threadIdx.x;
  const int a    = blockIdx.z;
  const int row0 = blockIdx.x * BM;
  const int col0 = blockIdx.y * BN;
  const short* Wb = Wp + (size_t)a * wPerAgent;
  constexpr int FM = BM/WM/16, FN = BN/WN/16;
  const int wid = tid >> 6, lane = tid & 63;
  const int wm = wid % WM, wn = wid / WM;
  const int rowB = wm*(BM/WM), colB = wn*(BN/WN);
  const int lrow = lane & 15, lq = lane >> 4;

  f32x4v acc[FM][FN];
  #pragma unroll
  for (int i = 0; i < FM; i++)
    #pragma unroll
    for (int j = 0; j < FN; j++) acc[i][j] = (f32x4v){0.f,0.f,0.f,0.f};

  for (int k0 = 0; k0 < K; k0 += 32){
    // ---- stage A tile (BM x 32) ----
    {
      constexpr int EA = BM/8;           // elems per thread (16 or 8)
      int r, kq;
      if constexpr (BM == 128){ r = tid >> 1; kq = (tid & 1)*16; }
      else                    { r = tid >> 2; kq = (tid & 3)*8;  }
      const size_t grow = (size_t)a*Bb + row0 + r;
      #pragma unroll
      for (int c8 = 0; c8 < EA; c8 += 8){
        const int f = k0 + kq + c8;       // multiple of 8; never crosses splits
        const short* sp;
        if constexpr (ASRC == 3)
          sp = (f < 256) ? (const short*)A1 + grow*(size_t)AP + f
                         : (const short*)A2 + grow*256 + (f - 256);
        else
          sp = (const short*)A1 + grow*(size_t)AP + f;
        *(bf16x8v*)&As[r*40 + kq + c8] = *(const bf16x8v*)sp;
      }
    }
    // ---- stage B tile (BN x 32) from W'[col][k] ----
    {
      if constexpr (BN == 512){
        const int n = tid;               // rows n and n+256, 4 reps each
        #pragma unroll
        for (int h = 0; h < 2; h++){
          const short* wp = Wb + (size_t)(col0 + n + h*256)*K + k0;
          #pragma unroll
          for (int t = 0; t < 4; t++)
            *(bf16x8v*)&Bs[(n + h*256)*40 + t*8] = *(const bf16x8v*)(wp + t*8);
        }
      } else {
        int n, kq, reps;
        if constexpr      (BN == 256){ n = tid;      kq = 0;            reps = 4; }
        else if constexpr (BN == 128){ n = tid >> 1; kq = (tid & 1)*16; reps = 2; }
        else                         { n = tid >> 2; kq = (tid & 3)*8;  reps = 1; }
        const short* wp = Wb + (size_t)(col0 + n)*K + k0 + kq;
        #pragma unroll
        for (int t = 0; t < reps; t++)
          *(bf16x8v*)&Bs[n*40 + kq + t*8] = *(const bf16x8v*)(wp + t*8);
      }
    }
    __syncthreads();
    // ---- fragments + MFMA ----
    bf16x8v af[FM], bfr[FN];
    #pragma unroll
    for (int mi = 0; mi < FM; mi++)
      af[mi] = *(const bf16x8v*)&As[(rowB + mi*16 + lrow)*40 + lq*8];
    #pragma unroll
    for (int ni = 0; ni < FN; ni++)
      bfr[ni] = *(const bf16x8v*)&Bs[(colB + ni*16 + lrow)*40 + lq*8];
    #pragma unroll
    for (int mi = 0; mi < FM; mi++)
      #pragma unroll
      for (int ni = 0; ni < FN; ni++)
        acc[mi][ni] = __builtin_amdgcn_mfma_f32_16x16x32_bf16(af[mi], bfr[ni], acc[mi][ni], 0, 0, 0);
    __syncthreads();
  }
  // ---- epilogue: C/D layout col=lane&15, row=quad*4+reg (m89/m91) ----
  #pragma unroll
  for (int mi = 0; mi < FM; mi++){
    const size_t gr = (size_t)a*Bb + row0 + rowB + mi*16 + lq*4;
    #pragma unroll
    for (int ni = 0; ni < FN; ni++){
      const int gc = col0 + colB + ni*16 + lrow;
      float bb; bool doact;
      if constexpr (MODE == 1){
        doact = (gc >= 256);
        bb = doact ? bias[gc - 256] : 0.f;
      } else {
        bb = bias ? bias[a*biasStride + gc] : 0.f;
        doact = ACT;
      }
      #pragma unroll
      for (int r = 0; r < 4; r++){
        float v = acc[mi][ni][r] + bb;
        if (doact) v = lrelu(v);
        if constexpr (OUTF32) ((float*)Out)[(gr + r)*(size_t)outPitch + gc] = v;
        else                  ((bf16*) Out)[(gr + r)*(size_t)outPitch + gc] = __float2bfloat16(v);
      }
    }
  }
}

// ---------------- attention: KV[row][512] (keys|vals), SEL in place ---------
union B8g { uint4 u; bf16 h[8]; };
__global__ __launch_bounds__(256) void attn_g(const bf16* __restrict__ KV,
                                              bf16* SO){
  const int t = blockIdx.x * 256 + threadIdx.x;   // (b*16 + e)
  const int e = t & 15;
  const size_t b = t >> 4;
  const size_t ofsKV = b*512 + e*16;
  const size_t ofsS  = b*256 + e*16;
  float S[4][16], Kf[4][16], Vf[4][16];
  #pragma unroll
  for (int i = 0; i < 4; i++){
    B8g u0, u1;
    const bf16* sp = SO + (size_t)i*Bb*256 + ofsS;
    u0.u = *(const uint4*)sp; u1.u = *(const uint4*)(sp + 8);
    #pragma unroll
    for (int l = 0; l < 8; l++){ S[i][l] = bf2f(u0.h[l]); S[i][8+l] = bf2f(u1.h[l]); }
    const bf16* kp = KV + (size_t)i*Bb*512 + ofsKV;
    u0.u = *(const uint4*)kp; u1.u = *(const uint4*)(kp + 8);
    #pragma unroll
    for (int l = 0; l < 8; l++){ Kf[i][l] = bf2f(u0.h[l]); Kf[i][8+l] = bf2f(u1.h[l]); }
    const bf16* vp = kp + 256;
    u0.u = *(const uint4*)vp; u1.u = *(const uint4*)(vp + 8);
    #pragma unroll
    for (int l = 0; l < 8; l++){ Vf[i][l] = bf2f(u0.h[l]); Vf[i][8+l] = bf2f(u1.h[l]); }
  }
  #pragma unroll
  for (int i = 0; i < 4; i++){
    float lg[4];
    #pragma unroll
    for (int j = 0; j < 4; j++){
      float d = 0.f;
      #pragma unroll
      for (int l = 0; l < 16; l++) d += S[i][l] * Kf[j][l];
      lg[j] = d * 0.25f;                 // / sqrt(16)
    }
    lg[i] = -1e9f;
    float m = fmaxf(fmaxf(lg[0], lg[1]), fmaxf(lg[2], lg[3]));
    float p[4], s = 0.f;
    #pragma unroll
    for (int j = 0; j < 4; j++){ p[j] = expf(lg[j] - m); s += p[j]; }
    p[i] = 0.f;
    const float inv = 1.f / s;
    float o[16] = {};
    #pragma unroll
    for (int j = 0; j < 4; j++){
      const float pj = p[j] * inv;
      #pragma unroll
      for (int l = 0; l < 16; l++) o[l] += pj * Vf[j][l];
    }
    B8g w0, w1;
    #pragma unroll
    for (int l = 0; l < 8; l++){ w0.h[l] = __float2bfloat16(o[l]); w1.h[l] = __float2bfloat16(o[8+l]); }
    bf16* op = SO + (size_t)i*Bb*256 + ofsS;
    *(uint4*)op       = w0.u;
    *(uint4*)(op + 8) = w1.u;
  }
}

// ---------------- argmax(actions) gather ------------------------------------
__global__ __launch_bounds__(256) void sel_q(const float* __restrict__ actions,
                                             const float* __restrict__ allq,
                                             float* __restrict__ out){
  const size_t i = (size_t)blockIdx.x * 256 + threadIdx.x;  // row = a*Bb + b
  const float* ap = actions + i*64;
  float best = ap[0]; int bi = 0;
  for (int j = 1; j < 64; j++){
    float v = ap[j];
    if (v > best){ best = v; bi = j; }   // first max, matches jnp.argmax
  }
  out[i] = allq[i*64 + bi];
}

// ================= fallback (round-5 verified fused pipeline) ================
constexpr int RB = 4;

template<int K>
__device__ __forceinline__ void gemm4_glb(const float* __restrict__ st,
                                          const float* __restrict__ ac,
                                          const float* __restrict__ mean,
                                          const float* __restrict__ rstd,
                                          int a, int brow0, int tid,
                                          const float* __restrict__ W,
                                          const float* __restrict__ bias, bool act,
                                          float (*Xs)[68], float (*Wt)[264],
                                          float (*Sout)[256]){
  const int r = tid >> 6, c4 = (tid & 63) * 4;
  float acc[4] = {};
  for (int k0 = 0; k0 < K; k0 += 8){
    if (tid < 32){
      const int rb = tid >> 3, kq = tid & 7;
      const int f = k0 + kq;
      float v = (f < Ss) ? st[((size_t)a*Bb + brow0 + rb)*Ss + f]
                         : ac[((size_t)a*Bb + brow0 + rb)*Av + (f - Ss)];
      Xs[kq][rb] = (v - mean[a*SA + f]) * rstd[a*SA + f];
    }
    {
      const int wk = tid >> 5, wc = (tid & 31) * 8;
      const float* wp = W + (size_t)(k0 + wk) * 256 + wc;
      *(float4*)&Wt[wk][wc]     = *(const float4*)wp;
      *(float4*)&Wt[wk][wc + 4] = *(const float4*)(wp + 4);
    }
    __syncthreads();
    #pragma unroll
    for (int kk = 0; kk < 8; kk++){
      const float av = Xs[kk][r];
      float4 w = *(const float4*)&Wt[kk][c4];
      acc[0] += av*w.x; acc[1] += av*w.y; acc[2] += av*w.z; acc[3] += av*w.w;
    }
    __syncthreads();
  }
  float4 o;
  o.x = acc[0] + (bias ? bias[c4+0] : 0.f);
  o.y = acc[1] + (bias ? bias[c4+1] : 0.f);
  o.z = acc[2] + (bias ? bias[c4+2] : 0.f);
  o.w = acc[3] + (bias ? bias[c4+3] : 0.f);
  if (act){ o.x = lrelu(o.x); o.y = lrelu(o.y); o.z = lrelu(o.z); o.w = lrelu(o.w); }
  *(float4*)&Sout[a*RB + r][c4] = o;
}

template<int K, bool HEAD>
__device__ __forceinline__ void gemm4_lds(const float (*S1)[256], const float (*S2)[256],
                                          int a, int tid,
                                          const float* __restrict__ W,
                                          const float* __restrict__ bias, bool act,
                                          float (*Wt)[264], float (*Sout)[256]){
  const int r = tid >> 6, c4 = (tid & 63) * 4;
  float acc[4] = {};
  for (int k0 = 0; k0 < K; k0 += 8){
    if (HEAD){
      const int wk = tid >> 5, c8 = (tid & 31) * 8;
      const int e = c8 >> 4, d0 = c8 & 15;
      const float* wp = W + (size_t)e*(256*16) + (size_t)(k0 + wk)*16 + d0;
      *(float4*)&Wt[wk][c8]     = *(const float4*)wp;
      *(float4*)&Wt[wk][c8 + 4] = *(const float4*)(wp + 4);
    } else {
      const int wk = tid >> 5, wc = (tid & 31) * 8;
      const float* wp = W + (size_t)(k0 + wk)*256 + wc;
      *(float4*)&Wt[wk][wc]     = *(const float4*)wp;
      *(float4*)&Wt[wk][wc + 4] = *(const float4*)(wp + 4);
    }
    __syncthreads();
    const float (*src)[256] = (k0 < 256) ? S1 : S2;
    const int kb = (k0 < 256) ? k0 : k0 - 256;
    const float* arow = &src[a*RB + r][kb];
    #pragma unroll
    for (int kk = 0; kk < 8; kk++){
      const float av = arow[kk];
      float4 w = *(const float4*)&Wt[kk][c4];
      acc[0] += av*w.x; acc[1] += av*w.y; acc[2] += av*w.z; acc[3] += av*w.w;
    }
    __syncthreads();
  }
  float4 o;
  o.x = acc[0] + (bias ? bias[c4+0] : 0.f);
  o.y = acc[1] + (bias ? bias[c4+1] : 0.f);
  o.z = acc[2] + (bias ? bias[c4+2] : 0.f);
  o.w = acc[3] + (bias ? bias[c4+3] : 0.f);
  if (act){ o.x = lrelu(o.x); o.y = lrelu(o.y); o.z = lrelu(o.z); o.w = lrelu(o.w); }
  *(float4*)&Sout[a*RB + r][c4] = o;
}

__global__ __launch_bounds__(256) void fused(
    const float* __restrict__ states, const float* __restrict__ actions,
    const float* __restrict__ mean,  const float* __restrict__ rstd,
    const float* __restrict__ Wenc, const float* __restrict__ benc,
    const float* __restrict__ Wsx,  const float* __restrict__ bsx,
    const float* __restrict__ Wk,   const float* __restrict__ Wsel,
    const float* __restrict__ Wv,   const float* __restrict__ bv,
    const float* __restrict__ Wc1,  const float* __restrict__ bc1,
    const float* __restrict__ Wc2,  const float* __restrict__ bc2,
    float* __restrict__ qout){
  __shared__ float A [16][256];
  __shared__ float Bs2[16][256];
  __shared__ float C [16][256];
  __shared__ float Wt[8][264];
  __shared__ float Xs[8][68];
  __shared__ float Cq[4][68];
  const int tid   = threadIdx.x;
  const int brow0 = blockIdx.x * RB;
  for (int a = 0; a < Nn; a++)
    gemm4_glb<Ss>(states, actions, mean, rstd, a, brow0, tid,
                  Wsx + (size_t)a*Ss*256, bsx + a*256, true, Xs, Wt, A);
  __syncthreads();
  for (int a = 0; a < Nn; a++)
    gemm4_lds<256, true>(A, nullptr, a, tid, Wsel, nullptr, false, Wt, C);
  __syncthreads();
  for (int a = 0; a < Nn; a++)
    gemm4_glb<SA>(states, actions, mean, rstd, a, brow0, tid,
                  Wenc + (size_t)a*SA*256, benc + a*256, true, Xs, Wt, A);
  __syncthreads();
  for (int a = 0; a < Nn; a++)
    gemm4_lds<256, true>(A, nullptr, a, tid, Wk, nullptr, false, Wt, Bs2);
  __syncthreads();
  for (int a = 0; a < Nn; a++)
    gemm4_lds<256, true>(A, nullptr, a, tid, Wv, bv, true, Wt, A);
  __syncthreads();
  if (tid < 64){
    const int rb = tid >> 4, e = tid & 15;
    const int co = e * 16;
    float S[4][16], Kf[4][16], Vf[4][16];
    #pragma unroll
    for (int i = 0; i < 4; i++)
      #pragma unroll
      for (int l = 0; l < 16; l++){
        S[i][l]  = C  [i*RB + rb][co + l];
        Kf[i][l] = Bs2[i*RB + rb][co + l];
        Vf[i][l] = A  [i*RB + rb][co + l];
      }
    #pragma unroll
    for (int i = 0; i < 4; i++){
      float lg[4];
      #pragma unroll
      for (int j = 0; j < 4; j++){
        float d = 0.f;
        #pragma unroll
        for (int l = 0; l < 16; l++) d += S[i][l] * Kf[j][l];
        lg[j] = d * 0.25f;
      }
      lg[i] = -1e9f;
      float m = fmaxf(fmaxf(lg[0], lg[1]), fmaxf(lg[2], lg[3]));
      float p[4], s = 0.f;
      #pragma unroll
      for (int j = 0; j < 4; j++){ p[j] = expf(lg[j] - m); s += p[j]; }
      p[i] = 0.f;
      const float inv = 1.f / s;
      float o[16] = {};
      #pragma unroll
      for (int j = 0; j < 4; j++){
        const float pj = p[j] * inv;
        #pragma unroll
        for (int l = 0; l < 16; l++) o[l] += pj * Vf[j][l];
      }
      #pragma unroll
      for (int l = 0; l < 16; l++) C[i*RB + rb][co + l] = o[l];
    }
  }
  __syncthreads();
  for (int a = 0; a < Nn; a++)
    gemm4_glb<Ss>(states, actions, mean, rstd, a, brow0, tid,
                  Wsx + (size_t)a*Ss*256, bsx + a*256, true, Xs, Wt, A);
  __syncthreads();
  for (int a = 0; a < Nn; a++)
    gemm4_lds<512, false>(A, C, a, tid, Wc1 + (size_t)a*512*256, bc1 + a*256, true, Wt, Bs2);
  __syncthreads();
  for (int a = 0; a < Nn; a++){
    const int r2 = tid >> 6, c2 = tid & 63;
    float acc = 0.f;
    for (int k0 = 0; k0 < 256; k0 += 8){
      const int wk = tid >> 5, wc = (tid & 31) * 2;
      const float* wp = Wc2 + (size_t)a*256*64 + (size_t)(k0 + wk)*64 + wc;
      Wt[wk][wc]     = wp[0];
      Wt[wk][wc + 1] = wp[1];
      __syncthreads();
      #pragma unroll
      for (int kk = 0; kk < 8; kk++) acc += Bs2[a*RB + r2][k0 + kk] * Wt[kk][c2];
      __syncthreads();
    }
    Cq[r2][c2] = acc + bc2[a*64 + c2];
    __syncthreads();
    if (tid < RB){
      const float* ap = actions + ((size_t)a*Bb + brow0 + tid)*Av;
      float best = ap[0]; int bi = 0;
      for (int j = 1; j < Av; j++){
        float v = ap[j];
        if (v > best){ best = v; bi = j; }
      }
      qout[(size_t)a*Bb + brow0 + tid] = Cq[tid][bi];
    }
    __syncthreads();
  }
}

// ================= host =====================================================
extern "C" void kernel_launch(void* const* d_in, const int* in_sizes, int n_in,
                              void* d_out, int out_size, void* d_ws, size_t ws_size,
                              hipStream_t stream){
  (void)in_sizes; (void)n_in; (void)out_size;
  const float* states  = (const float*)d_in[0];
  const float* actions = (const float*)d_in[1];
  const float* Wenc    = (const float*)d_in[2];
  const float* benc    = (const float*)d_in[3];
  const float* Wsx     = (const float*)d_in[4];
  const float* bsx     = (const float*)d_in[5];
  const float* Wk      = (const float*)d_in[6];
  const float* Wsel    = (const float*)d_in[7];
  const float* Wv      = (const float*)d_in[8];
  const float* bv      = (const float*)d_in[9];
  const float* Wc1     = (const float*)d_in[10];
  const float* bc1     = (const float*)d_in[11];
  const float* Wc2     = (const float*)d_in[12];
  const float* bc2     = (const float*)d_in[13];
  float* qout = (float*)d_out;

  char* base = (char*)d_ws;
  float* ssum = (float*)base;                 // 2304 f
  float* ssq  = ssum + Nn*SA;
  float* mean = ssq  + Nn*SA;
  float* rstd = mean + Nn*SA;
  size_t off = 4*Nn*SA*sizeof(float);         // 36864
  float* besc  = (float*)(base + off); off += Nn*512*sizeof(float);      // 8192
  short* Wes_p = (short*)(base + off); off += (size_t)Nn*512*SA*2;       // 2359296
  short* Wkv_p = (short*)(base + off); off += 512*256*2;                 // 262144
  short* Whs_p = (short*)(base + off); off += 256*256*2;                 // 131072
  short* Wc1_p = (short*)(base + off); off += (size_t)Nn*256*512*2;      // 1048576
  short* Wc2_p = (short*)(base + off); off += (size_t)Nn*64*256*2;       // 131072
  const size_t XBFB = (size_t)Nn*Bb*SA*2;     // 150,994,944 B
  const size_t W512 = (size_t)Nn*Bb*512*2;    // 134,217,728 B
  short* Xbf = (short*)(base + off);          // live: conv_stats .. enc GEMM
  bf16*  SEL = (bf16*)(base + off);           // carved from Xbf (born after enc)
  float* ALLQ= (float*)(base + off);          // carved from Xbf (born after c1)
  off += XBFB;
  bf16* ES = (bf16*)(base + off); off += W512;  // [row][512]: sa_enc | s_enc
  bf16* KV = (bf16*)(base + off); off += W512;  // [row][512]: keys | vals; later h
  bf16* H  = KV;                                // h reuses KV (dead after attn)
  const size_t need = off;

  hipMemsetAsync(ssum, 0, 2*Nn*SA*sizeof(float), stream);

  if (ws_size >= need){
    // single pass over fp32 inputs: bf16 convert + BN stats
    conv_stats<true><<<dim3(3, 64, Nn), dim3(64, 4), 0, stream>>>(states, actions, ssum, ssq, Xbf);
    bn_finalize<<<dim3(9), dim3(256), 0, stream>>>(ssum, ssq, mean, rstd);

    // combined bias init, then weight prep
    bias_copy<<<dim3(8), 256, 0, stream>>>(benc, bsx, besc);
    // Wes = [Wenc(cols 0-255, K=576) | Ws zero-padded to K=576 (cols 256-511)]
    foldT2<0><<<dim3(9, 4, Nn), 256, 0, stream>>>(Wenc, rstd, mean, besc,       Wes_p,            SA, SA, 256, 512*SA, 512);
    foldT2<0><<<dim3(9, 4, Nn), 256, 0, stream>>>(Wsx,  rstd, mean, besc + 256, Wes_p + 256*SA,   Ss, SA, 256, 512*SA, 512);
    // Wkv = [Wk(cols 0-255) | Wv(cols 256-511)], shared across agents
    foldT2<1><<<dim3(4, 4, 1), 256, 0, stream>>>(Wk,   nullptr, nullptr, nullptr, Wkv_p,           256, 256, 256, 0, 0);
    foldT2<1><<<dim3(4, 4, 1), 256, 0, stream>>>(Wv,   nullptr, nullptr, nullptr, Wkv_p + 256*256, 256, 256, 256, 0, 0);
    foldT2<1><<<dim3(4, 4, 1), 256, 0, stream>>>(Wsel, nullptr, nullptr, nullptr, Whs_p,           256, 256, 256, 0, 0);
    foldT2<0><<<dim3(8, 4, Nn), 256, 0, stream>>>(Wc1, nullptr, nullptr, nullptr, Wc1_p,           512, 512, 256, 256*512, 0);
    foldT2<0><<<dim3(4, 1, Nn), 256, 0, stream>>>(Wc2, nullptr, nullptr, nullptr, Wc2_p,           256, 256, 64,  64*256,  0);

    // ES = [sa_enc | s_enc] : one K=576 GEMM, A (Xbf) read once
    mgemm<64,512,1,4,576,2,SA,true,false,0><<<dim3(Bb/64, 1, Nn), 256, 0, stream>>>(
        Xbf, nullptr, Wes_p, 512*SA, besc, 512, ES, 512);
    // ---- Xbf dead; SEL lives at its base from here ----
    // KV = [keys | vals] : one GEMM over sa_enc (ES cols 0-255), split epilogue
    mgemm<64,512,1,4,256,2,512,false,false,1><<<dim3(Bb/64, 1, Nn), 256, 0, stream>>>(
        ES, nullptr, Wkv_p, 0, bv, 0, KV, 512);
    // SEL = s_enc @ Wsel  (A = ES cols 256-511)
    mgemm<64,256,1,4,256,2,512,false,false,0><<<dim3(Bb/64, 1, Nn), 256, 0, stream>>>(
        (const short*)ES + 256, nullptr, Whs_p, 0, nullptr, 0, SEL, 256);
    // SEL = other (in place)
    attn_g<<<dim3(Bb*16/256), 256, 0, stream>>>(KV, SEL);
    // H = lrelu([s_enc | other] @ Wc1 + bc1)  (KV dead -> reuse)
    mgemm<64,256,1,4,512,3,512,true,false,0><<<dim3(Bb/64, 1, Nn), 256, 0, stream>>>(
        (const short*)ES + 256, SEL, Wc1_p, 256*512, bc1, 256, H, 256);
    // ALLQ = h @ Wc2 + bc2 (fp32)  (SEL dead -> reuse Xbf base)
    mgemm<128,64,2,2,256,2,256,false,true,0><<<dim3(Bb/128, 1, Nn), 256, 0, stream>>>(
        H, nullptr, Wc2_p, 64*256, bc2, 64, ALLQ, 64);
    // gather argmax
    sel_q<<<dim3(Nn*Bb/256), 256, 0, stream>>>(actions, ALLQ, qout);
  } else {
    // verified fallback (stats-only pass; no Xbf write)
    conv_stats<false><<<dim3(3, 64, Nn), dim3(64, 4), 0, stream>>>(states, actions, ssum, ssq, nullptr);
    bn_finalize<<<dim3(9), dim3(256), 0, stream>>>(ssum, ssq, mean, rstd);
    fused<<<dim3(Bb/RB), 256, 0, stream>>>(states, actions, mean, rstd,
                                           Wenc, benc, Wsx, bsx,
                                           Wk, Wsel, Wv, bv,
                                           Wc1, bc1, Wc2, bc2, qout);
  }
}

// Round 4
// 910.816 us; speedup vs baseline: 1.3448x; 1.3448x over previous
//
#include <hip/hip_runtime.h>
#include <hip/hip_bf16.h>
#include <cstdint>
#include <cstddef>

using bf16 = __hip_bfloat16;
typedef __attribute__((ext_vector_type(8))) short bf16x8v;
typedef __attribute__((ext_vector_type(4))) short bf16x4v;
typedef __attribute__((ext_vector_type(4))) float f32x4v;

constexpr int Nn = 4;       // agents
constexpr int Bb = 32768;   // batch
constexpr int Ss = 512;     // state dim
constexpr int Av = 64;      // action dim
constexpr int SA = 576;     // S + A
constexpr float BN_EPS = 1e-5f;

__device__ __forceinline__ float lrelu(float v){ return v >= 0.f ? v : 0.01f * v; }
__device__ __forceinline__ float bf2f(bf16 x){ return __bfloat162float(x); }
__device__ __forceinline__ short f2bf(float v){
  union { bf16 b; short s; } u; u.b = __float2bfloat16(v); return u.s;
}

// async global->LDS, 16B per lane; LDS dest must be wave-uniform base (HW adds lane*16)
__device__ __forceinline__ void gload16(const void* g, void* l){
  __builtin_amdgcn_global_load_lds(
      (const __attribute__((address_space(1))) unsigned int*)g,
      (__attribute__((address_space(3))) unsigned int*)l, 16, 0, 0);
}

// ---------------- fused convert + BatchNorm statistics ----------------------
template<bool WRX>
__global__ __launch_bounds__(256) void conv_stats(const float* __restrict__ states,
                                                  const float* __restrict__ actions,
                                                  float* __restrict__ ssum,
                                                  float* __restrict__ ssq,
                                                  short* __restrict__ Xbf){
  const int n  = blockIdx.z;
  const int tx = threadIdx.x;
  const int ty = threadIdx.y;
  const int g  = blockIdx.x * 64 + tx;   // feature group of 4
  const bool on = g < (SA / 4);
  const int f  = g * 4;
  const float* p = nullptr; int step = 0;
  if (on){
    if (f < Ss){ p = states  + (size_t)n*Bb*Ss + f;        step = Ss; }
    else       { p = actions + (size_t)n*Bb*Av + (f - Ss); step = Av; }
  }
  float s0=0.f,s1=0.f,s2=0.f,s3=0.f,q0=0.f,q1=0.f,q2=0.f,q3=0.f;
  const int b0 = blockIdx.y * 512 + ty, bend = blockIdx.y * 512 + 512;
  if (on){
    for (int b = b0; b < bend; b += 4){
      float4 v = *(const float4*)(p + (size_t)b*step);
      if (WRX){
        short t4[4] __attribute__((aligned(8))) =
            { f2bf(v.x), f2bf(v.y), f2bf(v.z), f2bf(v.w) };
        *(bf16x4v*)&Xbf[((size_t)n*Bb + b)*SA + f] = *(bf16x4v*)t4;
      }
      s0 += v.x; q0 += v.x*v.x;
      s1 += v.y; q1 += v.y*v.y;
      s2 += v.z; q2 += v.z*v.z;
      s3 += v.w; q3 += v.w*v.w;
    }
  }
  __shared__ float rs[4][64][4], rq[4][64][4];
  rs[ty][tx][0]=s0; rs[ty][tx][1]=s1; rs[ty][tx][2]=s2; rs[ty][tx][3]=s3;
  rq[ty][tx][0]=q0; rq[ty][tx][1]=q1; rq[ty][tx][2]=q2; rq[ty][tx][3]=q3;
  __syncthreads();
  if (ty == 0 && on){
    #pragma unroll
    for (int j = 0; j < 4; j++){
      float ts = rs[0][tx][j]+rs[1][tx][j]+rs[2][tx][j]+rs[3][tx][j];
      float tq = rq[0][tx][j]+rq[1][tx][j]+rq[2][tx][j]+rq[3][tx][j];
      atomicAdd(&ssum[n*SA + f + j], ts);
      atomicAdd(&ssq [n*SA + f + j], tq);
    }
  }
}

__global__ void bn_finalize(const float* __restrict__ ssum, const float* __restrict__ ssq,
                            float* __restrict__ mean, float* __restrict__ rstd){
  int i = blockIdx.x * 256 + threadIdx.x;
  float m = ssum[i] * (1.f / Bb);
  float v = ssq[i] * (1.f / Bb) - m * m;
  v = fmaxf(v, 0.f);
  mean[i] = m;
  rstd[i] = rsqrtf(v + BN_EPS);
}

// ---------------- bias pre-init: besc[a][512] = [benc | bsx] ----------------
__global__ void bias_copy(const float* __restrict__ benc, const float* __restrict__ bsx,
                          float* __restrict__ besc){
  int i = blockIdx.x * 256 + threadIdx.x;
  if (i < Nn*512){
    int a = i >> 9, c = i & 511;
    besc[i] = (c < 256) ? benc[a*256 + c] : bsx[a*256 + (c - 256)];
  }
}

// ---------------- weight prep: transpose to [col][Kd] bf16, optional fold ---
template<int HEAD>
__global__ __launch_bounds__(256) void foldT2(const float* __restrict__ src,
                                              const float* __restrict__ scale,
                                              const float* __restrict__ mean,
                                              float* __restrict__ bias_out,
                                              short* __restrict__ dst,
                                              int Ks, int Kd, int N,
                                              int aDst, int biasStride){
  const int a  = blockIdx.z;
  const int tx = threadIdx.x & 63;
  const int ty = threadIdx.x >> 6;
  const int f0 = blockIdx.x * 64 + ty * 16;
  const int c  = blockIdx.y * 64 + tx;
  const float* s = src + (HEAD ? 0 : (size_t)a*Ks*N);
  short tmp[16] __attribute__((aligned(16)));
  float bsum = 0.f;
  #pragma unroll
  for (int j = 0; j < 16; j++){
    const int f = f0 + j;
    float w = 0.f;
    if (f < Ks){
      w = HEAD ? s[(((size_t)(c >> 4))*Ks + f)*16 + (c & 15)]
               : s[(size_t)f*N + c];
      if (scale) w *= scale[a*SA + f];
      if (mean)  bsum += mean[a*SA + f] * w;
    }
    tmp[j] = f2bf(w);
  }
  short* d = dst + (size_t)a*aDst + (size_t)c*Kd + f0;
  *(bf16x8v*)d       = *(bf16x8v*)tmp;
  *(bf16x8v*)(d + 8) = *(bf16x8v*)(tmp + 8);
  if (mean){
    __shared__ float red[4][64];
    red[ty][tx] = bsum;
    __syncthreads();
    if (threadIdx.x < 64){
      float t = red[0][threadIdx.x] + red[1][threadIdx.x]
              + red[2][threadIdx.x] + red[3][threadIdx.x];
      atomicAdd(&bias_out[a*biasStride + blockIdx.y*64 + threadIdx.x], -t);
    }
  }
}

// ---------------- MFMA GEMM (m97-style: linear LDS + global_load_lds) -------
// C[a*Bb+row][col] = act( A[row][0..K) @ W'[col][0..K)^T + bias )
// W' layout: [col][K] bf16 (k-contiguous), per-agent stride wPerAgent elems.
// ASRC: 2 bf16 pitch AP; 3 bf16 concat A1(pitch AP)|A2(pitch 256), split at 256.
// MODE: 0 normal (bias[a*biasStride+gc], ACT); 1 kv-split: gc<256 raw,
//       gc>=256 -> + bias[gc-256], lrelu.
// 256 threads = 4 waves, wave tile (BM/WM)x(BN/WN) must be 64x64 (or 64x16).
template<int BM,int BN,int WM,int WN,int K,int ASRC,int AP,bool ACT,bool OUTF32,int MODE>
__global__ __launch_bounds__(256) void mgemm2(const void* A1, const void* A2,
                                              const short* __restrict__ Wp, int wPerAgent,
                                              const float* __restrict__ bias, int biasStride,
                                              void* Out, int outPitch){
  __shared__ __align__(16) short As[BM*32];
  __shared__ __align__(16) short Bs[BN*32];
  const int tid  = threadIdx.x;
  const int a    = blockIdx.z;
  const int row0 = blockIdx.x * BM;
  const int col0 = blockIdx.y * BN;
  const short* Wb = Wp + (size_t)a * wPerAgent;
  constexpr int FM = BM/WM/16, FN = BN/WN/16;
  const int wid = tid >> 6, lane = tid & 63;
  const int wm = wid % WM, wn = wid / WM;
  const int rowB = wm*(BM/WM), colB = wn*(BN/WN);
  const int lrow = lane & 15, lq = lane >> 4;
  const int srow = lane >> 2;          // staging: row within 16-row block
  const int skc  = (lane & 3) * 8;     // staging: k-offset (shorts)

  f32x4v acc[FM][FN];
  #pragma unroll
  for (int i = 0; i < FM; i++)
    #pragma unroll
    for (int j = 0; j < FN; j++) acc[i][j] = (f32x4v){0.f,0.f,0.f,0.f};

  constexpr int AB = BM/16;   // 16-row staging blocks for A (4 or 8)
  constexpr int BB = BN/16;   // for B (4 or 16)

  for (int k0 = 0; k0 < K; k0 += 32){
    // ---- stage A tile (BM x 32) via global_load_lds, 1KB per wave-call ----
    #pragma unroll
    for (int t = 0; t < AB/4; t++){
      const int bb = wid + t*4;                 // wave-uniform block index
      const int r  = bb*16 + srow;
      const int f  = k0 + skc;
      const short* src;
      if constexpr (ASRC == 3)
        src = (f < 256) ? (const short*)A1 + ((size_t)a*Bb + row0 + r)*(size_t)AP + f
                        : (const short*)A2 + ((size_t)a*Bb + row0 + r)*256 + (f - 256);
      else
        src = (const short*)A1 + ((size_t)a*Bb + row0 + r)*(size_t)AP + f;
      gload16(src, &As[bb*512]);
    }
    // ---- stage B tile (BN x 32) from W'[col][k] ----
    #pragma unroll
    for (int t = 0; t < BB/4; t++){
      const int bb = wid + t*4;
      const int r  = bb*16 + srow;
      const short* src = Wb + (size_t)(col0 + r)*K + k0 + skc;
      gload16(src, &Bs[bb*512]);
    }
    __syncthreads();                            // compiler drains vmcnt here
    // ---- fragments + MFMA ----
    bf16x8v af[FM], bfr[FN];
    #pragma unroll
    for (int mi = 0; mi < FM; mi++)
      af[mi] = *(const bf16x8v*)&As[(rowB + mi*16 + lrow)*32 + lq*8];
    #pragma unroll
    for (int ni = 0; ni < FN; ni++)
      bfr[ni] = *(const bf16x8v*)&Bs[(colB + ni*16 + lrow)*32 + lq*8];
    #pragma unroll
    for (int mi = 0; mi < FM; mi++)
      #pragma unroll
      for (int ni = 0; ni < FN; ni++)
        acc[mi][ni] = __builtin_amdgcn_mfma_f32_16x16x32_bf16(af[mi], bfr[ni], acc[mi][ni], 0, 0, 0);
    __syncthreads();
  }
  // ---- epilogue: C/D layout col=lane&15, row=quad*4+reg (m89/m91) ----
  #pragma unroll
  for (int mi = 0; mi < FM; mi++){
    const size_t gr = (size_t)a*Bb + row0 + rowB + mi*16 + lq*4;
    #pragma unroll
    for (int ni = 0; ni < FN; ni++){
      const int gc = col0 + colB + ni*16 + lrow;
      float bb; bool doact;
      if constexpr (MODE == 1){
        doact = (gc >= 256);
        bb = doact ? bias[gc - 256] : 0.f;
      } else {
        bb = bias ? bias[a*biasStride + gc] : 0.f;
        doact = ACT;
      }
      #pragma unroll
      for (int r = 0; r < 4; r++){
        float v = acc[mi][ni][r] + bb;
        if (doact) v = lrelu(v);
        if constexpr (OUTF32) ((float*)Out)[(gr + r)*(size_t)outPitch + gc] = v;
        else                  ((bf16*) Out)[(gr + r)*(size_t)outPitch + gc] = __float2bfloat16(v);
      }
    }
  }
}

// ---------------- attention: KV[row][512] (keys|vals), SEL in place ---------
union B8g { uint4 u; bf16 h[8]; };
__global__ __launch_bounds__(256) void attn_g(const bf16* __restrict__ KV,
                                              bf16* SO){
  const int t = blockIdx.x * 256 + threadIdx.x;   // (b*16 + e)
  const int e = t & 15;
  const size_t b = t >> 4;
  const size_t ofsKV = b*512 + e*16;
  const size_t ofsS  = b*256 + e*16;
  float S[4][16], Kf[4][16], Vf[4][16];
  #pragma unroll
  for (int i = 0; i < 4; i++){
    B8g u0, u1;
    const bf16* sp = SO + (size_t)i*Bb*256 + ofsS;
    u0.u = *(const uint4*)sp; u1.u = *(const uint4*)(sp + 8);
    #pragma unroll
    for (int l = 0; l < 8; l++){ S[i][l] = bf2f(u0.h[l]); S[i][8+l] = bf2f(u1.h[l]); }
    const bf16* kp = KV + (size_t)i*Bb*512 + ofsKV;
    u0.u = *(const uint4*)kp; u1.u = *(const uint4*)(kp + 8);
    #pragma unroll
    for (int l = 0; l < 8; l++){ Kf[i][l] = bf2f(u0.h[l]); Kf[i][8+l] = bf2f(u1.h[l]); }
    const bf16* vp = kp + 256;
    u0.u = *(const uint4*)vp; u1.u = *(const uint4*)(vp + 8);
    #pragma unroll
    for (int l = 0; l < 8; l++){ Vf[i][l] = bf2f(u0.h[l]); Vf[i][8+l] = bf2f(u1.h[l]); }
  }
  #pragma unroll
  for (int i = 0; i < 4; i++){
    float lg[4];
    #pragma unroll
    for (int j = 0; j < 4; j++){
      float d = 0.f;
      #pragma unroll
      for (int l = 0; l < 16; l++) d += S[i][l] * Kf[j][l];
      lg[j] = d * 0.25f;                 // / sqrt(16)
    }
    lg[i] = -1e9f;
    float m = fmaxf(fmaxf(lg[0], lg[1]), fmaxf(lg[2], lg[3]));
    float p[4], s = 0.f;
    #pragma unroll
    for (int j = 0; j < 4; j++){ p[j] = expf(lg[j] - m); s += p[j]; }
    p[i] = 0.f;
    const float inv = 1.f / s;
    float o[16] = {};
    #pragma unroll
    for (int j = 0; j < 4; j++){
      const float pj = p[j] * inv;
      #pragma unroll
      for (int l = 0; l < 16; l++) o[l] += pj * Vf[j][l];
    }
    B8g w0, w1;
    #pragma unroll
    for (int l = 0; l < 8; l++){ w0.h[l] = __float2bfloat16(o[l]); w1.h[l] = __float2bfloat16(o[8+l]); }
    bf16* op = SO + (size_t)i*Bb*256 + ofsS;
    *(uint4*)op       = w0.u;
    *(uint4*)(op + 8) = w1.u;
  }
}

// ---------------- argmax(actions) gather ------------------------------------
__global__ __launch_bounds__(256) void sel_q(const float* __restrict__ actions,
                                             const float* __restrict__ allq,
                                             float* __restrict__ out){
  const size_t i = (size_t)blockIdx.x * 256 + threadIdx.x;  // row = a*Bb + b
  const float* ap = actions + i*64;
  float best = ap[0]; int bi = 0;
  for (int j = 1; j < 64; j++){
    float v = ap[j];
    if (v > best){ best = v; bi = j; }   // first max, matches jnp.argmax
  }
  out[i] = allq[i*64 + bi];
}

// ================= fallback (round-5 verified fused pipeline) ================
constexpr int RB = 4;

template<int K>
__device__ __forceinline__ void gemm4_glb(const float* __restrict__ st,
                                          const float* __restrict__ ac,
                                          const float* __restrict__ mean,
                                          const float* __restrict__ rstd,
                                          int a, int brow0, int tid,
                                          const float* __restrict__ W,
                                          const float* __restrict__ bias, bool act,
                                          float (*Xs)[68], float (*Wt)[264],
                                          float (*Sout)[256]){
  const int r = tid >> 6, c4 = (tid & 63) * 4;
  float acc[4] = {};
  for (int k0 = 0; k0 < K; k0 += 8){
    if (tid < 32){
      const int rb = tid >> 3, kq = tid & 7;
      const int f = k0 + kq;
      float v = (f < Ss) ? st[((size_t)a*Bb + brow0 + rb)*Ss + f]
                         : ac[((size_t)a*Bb + brow0 + rb)*Av + (f - Ss)];
      Xs[kq][rb] = (v - mean[a*SA + f]) * rstd[a*SA + f];
    }
    {
      const int wk = tid >> 5, wc = (tid & 31) * 8;
      const float* wp = W + (size_t)(k0 + wk) * 256 + wc;
      *(float4*)&Wt[wk][wc]     = *(const float4*)wp;
      *(float4*)&Wt[wk][wc + 4] = *(const float4*)(wp + 4);
    }
    __syncthreads();
    #pragma unroll
    for (int kk = 0; kk < 8; kk++){
      const float av = Xs[kk][r];
      float4 w = *(const float4*)&Wt[kk][c4];
      acc[0] += av*w.x; acc[1] += av*w.y; acc[2] += av*w.z; acc[3] += av*w.w;
    }
    __syncthreads();
  }
  float4 o;
  o.x = acc[0] + (bias ? bias[c4+0] : 0.f);
  o.y = acc[1] + (bias ? bias[c4+1] : 0.f);
  o.z = acc[2] + (bias ? bias[c4+2] : 0.f);
  o.w = acc[3] + (bias ? bias[c4+3] : 0.f);
  if (act){ o.x = lrelu(o.x); o.y = lrelu(o.y); o.z = lrelu(o.z); o.w = lrelu(o.w); }
  *(float4*)&Sout[a*RB + r][c4] = o;
}

template<int K, bool HEAD>
__device__ __forceinline__ void gemm4_lds(const float (*S1)[256], const float (*S2)[256],
                                          int a, int tid,
                                          const float* __restrict__ W,
                                          const float* __restrict__ bias, bool act,
                                          float (*Wt)[264], float (*Sout)[256]){
  const int r = tid >> 6, c4 = (tid & 63) * 4;
  float acc[4] = {};
  for (int k0 = 0; k0 < K; k0 += 8){
    if (HEAD){
      const int wk = tid >> 5, c8 = (tid & 31) * 8;
      const int e = c8 >> 4, d0 = c8 & 15;
      const float* wp = W + (size_t)e*(256*16) + (size_t)(k0 + wk)*16 + d0;
      *(float4*)&Wt[wk][c8]     = *(const float4*)wp;
      *(float4*)&Wt[wk][c8 + 4] = *(const float4*)(wp + 4);
    } else {
      const int wk = tid >> 5, wc = (tid & 31) * 8;
      const float* wp = W + (size_t)(k0 + wk)*256 + wc;
      *(float4*)&Wt[wk][wc]     = *(const float4*)wp;
      *(float4*)&Wt[wk][wc + 4] = *(const float4*)(wp + 4);
    }
    __syncthreads();
    const float (*src)[256] = (k0 < 256) ? S1 : S2;
    const int kb = (k0 < 256) ? k0 : k0 - 256;
    const float* arow = &src[a*RB + r][kb];
    #pragma unroll
    for (int kk = 0; kk < 8; kk++){
      const float av = arow[kk];
      float4 w = *(const float4*)&Wt[kk][c4];
      acc[0] += av*w.x; acc[1] += av*w.y; acc[2] += av*w.z; acc[3] += av*w.w;
    }
    __syncthreads();
  }
  float4 o;
  o.x = acc[0] + (bias ? bias[c4+0] : 0.f);
  o.y = acc[1] + (bias ? bias[c4+1] : 0.f);
  o.z = acc[2] + (bias ? bias[c4+2] : 0.f);
  o.w = acc[3] + (bias ? bias[c4+3] : 0.f);
  if (act){ o.x = lrelu(o.x); o.y = lrelu(o.y); o.z = lrelu(o.z); o.w = lrelu(o.w); }
  *(float4*)&Sout[a*RB + r][c4] = o;
}

__global__ __launch_bounds__(256) void fused(
    const float* __restrict__ states, const float* __restrict__ actions,
    const float* __restrict__ mean,  const float* __restrict__ rstd,
    const float* __restrict__ Wenc, const float* __restrict__ benc,
    const float* __restrict__ Wsx,  const float* __restrict__ bsx,
    const float* __restrict__ Wk,   const float* __restrict__ Wsel,
    const float* __restrict__ Wv,   const float* __restrict__ bv,
    const float* __restrict__ Wc1,  const float* __restrict__ bc1,
    const float* __restrict__ Wc2,  const float* __restrict__ bc2,
    float* __restrict__ qout){
  __shared__ float A [16][256];
  __shared__ float Bs2[16][256];
  __shared__ float C [16][256];
  __shared__ float Wt[8][264];
  __shared__ float Xs[8][68];
  __shared__ float Cq[4][68];
  const int tid   = threadIdx.x;
  const int brow0 = blockIdx.x * RB;
  for (int a = 0; a < Nn; a++)
    gemm4_glb<Ss>(states, actions, mean, rstd, a, brow0, tid,
                  Wsx + (size_t)a*Ss*256, bsx + a*256, true, Xs, Wt, A);
  __syncthreads();
  for (int a = 0; a < Nn; a++)
    gemm4_lds<256, true>(A, nullptr, a, tid, Wsel, nullptr, false, Wt, C);
  __syncthreads();
  for (int a = 0; a < Nn; a++)
    gemm4_glb<SA>(states, actions, mean, rstd, a, brow0, tid,
                  Wenc + (size_t)a*SA*256, benc + a*256, true, Xs, Wt, A);
  __syncthreads();
  for (int a = 0; a < Nn; a++)
    gemm4_lds<256, true>(A, nullptr, a, tid, Wk, nullptr, false, Wt, Bs2);
  __syncthreads();
  for (int a = 0; a < Nn; a++)
    gemm4_lds<256, true>(A, nullptr, a, tid, Wv, bv, true, Wt, A);
  __syncthreads();
  if (tid < 64){
    const int rb = tid >> 4, e = tid & 15;
    const int co = e * 16;
    float S[4][16], Kf[4][16], Vf[4][16];
    #pragma unroll
    for (int i = 0; i < 4; i++)
      #pragma unroll
      for (int l = 0; l < 16; l++){
        S[i][l]  = C  [i*RB + rb][co + l];
        Kf[i][l] = Bs2[i*RB + rb][co + l];
        Vf[i][l] = A  [i*RB + rb][co + l];
      }
    #pragma unroll
    for (int i = 0; i < 4; i++){
      float lg[4];
      #pragma unroll
      for (int j = 0; j < 4; j++){
        float d = 0.f;
        #pragma unroll
        for (int l = 0; l < 16; l++) d += S[i][l] * Kf[j][l];
        lg[j] = d * 0.25f;
      }
      lg[i] = -1e9f;
      float m = fmaxf(fmaxf(lg[0], lg[1]), fmaxf(lg[2], lg[3]));
      float p[4], s = 0.f;
      #pragma unroll
      for (int j = 0; j < 4; j++){ p[j] = expf(lg[j] - m); s += p[j]; }
      p[i] = 0.f;
      const float inv = 1.f / s;
      float o[16] = {};
      #pragma unroll
      for (int j = 0; j < 4; j++){
        const float pj = p[j] * inv;
        #pragma unroll
        for (int l = 0; l < 16; l++) o[l] += pj * Vf[j][l];
      }
      #pragma unroll
      for (int l = 0; l < 16; l++) C[i*RB + rb][co + l] = o[l];
    }
  }
  __syncthreads();
  for (int a = 0; a < Nn; a++)
    gemm4_glb<Ss>(states, actions, mean, rstd, a, brow0, tid,
                  Wsx + (size_t)a*Ss*256, bsx + a*256, true, Xs, Wt, A);
  __syncthreads();
  for (int a = 0; a < Nn; a++)
    gemm4_lds<512, false>(A, C, a, tid, Wc1 + (size_t)a*512*256, bc1 + a*256, true, Wt, Bs2);
  __syncthreads();
  for (int a = 0; a < Nn; a++){
    const int r2 = tid >> 6, c2 = tid & 63;
    float acc = 0.f;
    for (int k0 = 0; k0 < 256; k0 += 8){
      const int wk = tid >> 5, wc = (tid & 31) * 2;
      const float* wp = Wc2 + (size_t)a*256*64 + (size_t)(k0 + wk)*64 + wc;
      Wt[wk][wc]     = wp[0];
      Wt[wk][wc + 1] = wp[1];
      __syncthreads();
      #pragma unroll
      for (int kk = 0; kk < 8; kk++) acc += Bs2[a*RB + r2][k0 + kk] * Wt[kk][c2];
      __syncthreads();
    }
    Cq[r2][c2] = acc + bc2[a*64 + c2];
    __syncthreads();
    if (tid < RB){
      const float* ap = actions + ((size_t)a*Bb + brow0 + tid)*Av;
      float best = ap[0]; int bi = 0;
      for (int j = 1; j < Av; j++){
        float v = ap[j];
        if (v > best){ best = v; bi = j; }
      }
      qout[(size_t)a*Bb + brow0 + tid] = Cq[tid][bi];
    }
    __syncthreads();
  }
}

// ================= host =====================================================
extern "C" void kernel_launch(void* const* d_in, const int* in_sizes, int n_in,
                              void* d_out, int out_size, void* d_ws, size_t ws_size,
                              hipStream_t stream){
  (void)in_sizes; (void)n_in; (void)out_size;
  const float* states  = (const float*)d_in[0];
  const float* actions = (const float*)d_in[1];
  const float* Wenc    = (const float*)d_in[2];
  const float* benc    = (const float*)d_in[3];
  const float* Wsx     = (const float*)d_in[4];
  const float* bsx     = (const float*)d_in[5];
  const float* Wk      = (const float*)d_in[6];
  const float* Wsel    = (const float*)d_in[7];
  const float* Wv      = (const float*)d_in[8];
  const float* bv      = (const float*)d_in[9];
  const float* Wc1     = (const float*)d_in[10];
  const float* bc1     = (const float*)d_in[11];
  const float* Wc2     = (const float*)d_in[12];
  const float* bc2     = (const float*)d_in[13];
  float* qout = (float*)d_out;

  char* base = (char*)d_ws;
  float* ssum = (float*)base;                 // 2304 f
  float* ssq  = ssum + Nn*SA;
  float* mean = ssq  + Nn*SA;
  float* rstd = mean + Nn*SA;
  size_t off = 4*Nn*SA*sizeof(float);         // 36864
  float* besc  = (float*)(base + off); off += Nn*512*sizeof(float);      // 8192
  short* Wes_p = (short*)(base + off); off += (size_t)Nn*512*SA*2;       // 2359296
  short* Wkv_p = (short*)(base + off); off += 512*256*2;                 // 262144
  short* Whs_p = (short*)(base + off); off += 256*256*2;                 // 131072
  short* Wc1_p = (short*)(base + off); off += (size_t)Nn*256*512*2;      // 1048576
  short* Wc2_p = (short*)(base + off); off += (size_t)Nn*64*256*2;       // 131072
  const size_t XBFB = (size_t)Nn*Bb*SA*2;     // 150,994,944 B
  const size_t W512 = (size_t)Nn*Bb*512*2;    // 134,217,728 B
  short* Xbf = (short*)(base + off);          // live: conv_stats .. ES GEMM
  bf16*  SEL = (bf16*)(base + off);           // carved from Xbf (born after ES)
  float* ALLQ= (float*)(base + off);          // carved from Xbf (born after c1)
  off += XBFB;
  bf16* ES = (bf16*)(base + off); off += W512;  // [row][512]: sa_enc | s_enc
  bf16* KV = (bf16*)(base + off); off += W512;  // [row][512]: keys | vals; later h
  bf16* H  = KV;                                // h reuses KV (dead after attn)
  const size_t need = off;

  hipMemsetAsync(ssum, 0, 2*Nn*SA*sizeof(float), stream);

  if (ws_size >= need){
    // single pass over fp32 inputs: bf16 convert + BN stats
    conv_stats<true><<<dim3(3, 64, Nn), dim3(64, 4), 0, stream>>>(states, actions, ssum, ssq, Xbf);
    bn_finalize<<<dim3(9), dim3(256), 0, stream>>>(ssum, ssq, mean, rstd);

    // combined bias init, then weight prep
    bias_copy<<<dim3(8), 256, 0, stream>>>(benc, bsx, besc);
    // Wes = [Wenc(cols 0-255, K=576) | Ws zero-padded to K=576 (cols 256-511)]
    foldT2<0><<<dim3(9, 4, Nn), 256, 0, stream>>>(Wenc, rstd, mean, besc,       Wes_p,            SA, SA, 256, 512*SA, 512);
    foldT2<0><<<dim3(9, 4, Nn), 256, 0, stream>>>(Wsx,  rstd, mean, besc + 256, Wes_p + 256*SA,   Ss, SA, 256, 512*SA, 512);
    // Wkv = [Wk(cols 0-255) | Wv(cols 256-511)], shared across agents
    foldT2<1><<<dim3(4, 4, 1), 256, 0, stream>>>(Wk,   nullptr, nullptr, nullptr, Wkv_p,           256, 256, 256, 0, 0);
    foldT2<1><<<dim3(4, 4, 1), 256, 0, stream>>>(Wv,   nullptr, nullptr, nullptr, Wkv_p + 256*256, 256, 256, 256, 0, 0);
    foldT2<1><<<dim3(4, 4, 1), 256, 0, stream>>>(Wsel, nullptr, nullptr, nullptr, Whs_p,           256, 256, 256, 0, 0);
    foldT2<0><<<dim3(8, 4, Nn), 256, 0, stream>>>(Wc1, nullptr, nullptr, nullptr, Wc1_p,           512, 512, 256, 256*512, 0);
    foldT2<0><<<dim3(4, 1, Nn), 256, 0, stream>>>(Wc2, nullptr, nullptr, nullptr, Wc2_p,           256, 256, 64,  64*256,  0);

    // ES = [sa_enc | s_enc] : K=576 GEMM, gy=2 col-tiles (A read twice, bf16)
    mgemm2<64,256,1,4,576,2,SA,true,false,0><<<dim3(Bb/64, 2, Nn), 256, 0, stream>>>(
        Xbf, nullptr, Wes_p, 512*SA, besc, 512, ES, 512);
    // ---- Xbf dead; SEL lives at its base from here ----
    // KV = [keys | vals] : one GEMM over sa_enc (ES cols 0-255), split epilogue
    mgemm2<64,256,1,4,256,2,512,false,false,1><<<dim3(Bb/64, 2, Nn), 256, 0, stream>>>(
        ES, nullptr, Wkv_p, 0, bv, 0, KV, 512);
    // SEL = s_enc @ Wsel  (A = ES cols 256-511)
    mgemm2<64,256,1,4,256,2,512,false,false,0><<<dim3(Bb/64, 1, Nn), 256, 0, stream>>>(
        (const short*)ES + 256, nullptr, Whs_p, 0, nullptr, 0, SEL, 256);
    // SEL = other (in place)
    attn_g<<<dim3(Bb*16/256), 256, 0, stream>>>(KV, SEL);
    // H = lrelu([s_enc | other] @ Wc1 + bc1)  (KV dead -> reuse)
    mgemm2<64,256,1,4,512,3,512,true,false,0><<<dim3(Bb/64, 1, Nn), 256, 0, stream>>>(
        (const short*)ES + 256, SEL, Wc1_p, 256*512, bc1, 256, H, 256);
    // ALLQ = h @ Wc2 + bc2 (fp32)  (SEL dead -> reuse Xbf base)
    mgemm2<64,64,1,4,256,2,256,false,true,0><<<dim3(Bb/64, 1, Nn), 256, 0, stream>>>(
        H, nullptr, Wc2_p, 64*256, bc2, 64, ALLQ, 64);
    // gather argmax
    sel_q<<<dim3(Nn*Bb/256), 256, 0, stream>>>(actions, ALLQ, qout);
  } else {
    // verified fallback (stats-only pass; no Xbf write)
    conv_stats<false><<<dim3(3, 64, Nn), dim3(64, 4), 0, stream>>>(states, actions, ssum, ssq, nullptr);
    bn_finalize<<<dim3(9), dim3(256), 0, stream>>>(ssum, ssq, mean, rstd);
    fused<<<dim3(Bb/RB), 256, 0, stream>>>(states, actions, mean, rstd,
                                           Wenc, benc, Wsx, bsx,
                                           Wk, Wsel, Wv, bv,
                                           Wc1, bc1, Wc2, bc2, qout);
  }
}

// Round 5
// 909.481 us; speedup vs baseline: 1.3468x; 1.0015x over previous
//
#include <hip/hip_runtime.h>
#include <hip/hip_bf16.h>
#include <cstdint>
#include <cstddef>

using bf16 = __hip_bfloat16;
typedef __attribute__((ext_vector_type(8))) short bf16x8v;
typedef __attribute__((ext_vector_type(4))) short bf16x4v;
typedef __attribute__((ext_vector_type(4))) float f32x4v;

constexpr int Nn = 4;       // agents
constexpr int Bb = 32768;   // batch
constexpr int Ss = 512;     // state dim
constexpr int Av = 64;      // action dim
constexpr int SA = 576;     // S + A
constexpr float BN_EPS = 1e-5f;

__device__ __forceinline__ float lrelu(float v){ return v >= 0.f ? v : 0.01f * v; }
__device__ __forceinline__ float bf2f(bf16 x){ return __bfloat162float(x); }
__device__ __forceinline__ short f2bf(float v){
  union { bf16 b; short s; } u; u.b = __float2bfloat16(v); return u.s;
}

// async global->LDS, 16B per lane; LDS dest must be wave-uniform base (HW adds lane*16)
__device__ __forceinline__ void gload16(const void* g, void* l){
  __builtin_amdgcn_global_load_lds(
      (const __attribute__((address_space(1))) unsigned int*)g,
      (__attribute__((address_space(3))) unsigned int*)l, 16, 0, 0);
}

// ---------------- fused convert + BatchNorm statistics ----------------------
template<bool WRX>
__global__ __launch_bounds__(256) void conv_stats(const float* __restrict__ states,
                                                  const float* __restrict__ actions,
                                                  float* __restrict__ ssum,
                                                  float* __restrict__ ssq,
                                                  short* __restrict__ Xbf){
  const int n  = blockIdx.z;
  const int tx = threadIdx.x;
  const int ty = threadIdx.y;
  const int g  = blockIdx.x * 64 + tx;   // feature group of 4
  const bool on = g < (SA / 4);
  const int f  = g * 4;
  const float* p = nullptr; int step = 0;
  if (on){
    if (f < Ss){ p = states  + (size_t)n*Bb*Ss + f;        step = Ss; }
    else       { p = actions + (size_t)n*Bb*Av + (f - Ss); step = Av; }
  }
  float s0=0.f,s1=0.f,s2=0.f,s3=0.f,q0=0.f,q1=0.f,q2=0.f,q3=0.f;
  const int b0 = blockIdx.y * 512 + ty, bend = blockIdx.y * 512 + 512;
  if (on){
    for (int b = b0; b < bend; b += 4){
      float4 v = *(const float4*)(p + (size_t)b*step);
      if (WRX){
        short t4[4] __attribute__((aligned(8))) =
            { f2bf(v.x), f2bf(v.y), f2bf(v.z), f2bf(v.w) };
        *(bf16x4v*)&Xbf[((size_t)n*Bb + b)*SA + f] = *(bf16x4v*)t4;
      }
      s0 += v.x; q0 += v.x*v.x;
      s1 += v.y; q1 += v.y*v.y;
      s2 += v.z; q2 += v.z*v.z;
      s3 += v.w; q3 += v.w*v.w;
    }
  }
  __shared__ float rs[4][64][4], rq[4][64][4];
  rs[ty][tx][0]=s0; rs[ty][tx][1]=s1; rs[ty][tx][2]=s2; rs[ty][tx][3]=s3;
  rq[ty][tx][0]=q0; rq[ty][tx][1]=q1; rq[ty][tx][2]=q2; rq[ty][tx][3]=q3;
  __syncthreads();
  if (ty == 0 && on){
    #pragma unroll
    for (int j = 0; j < 4; j++){
      float ts = rs[0][tx][j]+rs[1][tx][j]+rs[2][tx][j]+rs[3][tx][j];
      float tq = rq[0][tx][j]+rq[1][tx][j]+rq[2][tx][j]+rq[3][tx][j];
      atomicAdd(&ssum[n*SA + f + j], ts);
      atomicAdd(&ssq [n*SA + f + j], tq);
    }
  }
}

__global__ void bn_finalize(const float* __restrict__ ssum, const float* __restrict__ ssq,
                            float* __restrict__ mean, float* __restrict__ rstd){
  int i = blockIdx.x * 256 + threadIdx.x;
  float m = ssum[i] * (1.f / Bb);
  float v = ssq[i] * (1.f / Bb) - m * m;
  v = fmaxf(v, 0.f);
  mean[i] = m;
  rstd[i] = rsqrtf(v + BN_EPS);
}

// ---------------- bias pre-init: besc[a][512] = [benc | bsx] ----------------
__global__ void bias_copy(const float* __restrict__ benc, const float* __restrict__ bsx,
                          float* __restrict__ besc){
  int i = blockIdx.x * 256 + threadIdx.x;
  if (i < Nn*512){
    int a = i >> 9, c = i & 511;
    besc[i] = (c < 256) ? benc[a*256 + c] : bsx[a*256 + (c - 256)];
  }
}

// ---------------- weight prep: transpose to [col][Kd] bf16, optional fold ---
template<int HEAD>
__global__ __launch_bounds__(256) void foldT2(const float* __restrict__ src,
                                              const float* __restrict__ scale,
                                              const float* __restrict__ mean,
                                              float* __restrict__ bias_out,
                                              short* __restrict__ dst,
                                              int Ks, int Kd, int N,
                                              int aDst, int biasStride){
  const int a  = blockIdx.z;
  const int tx = threadIdx.x & 63;
  const int ty = threadIdx.x >> 6;
  const int f0 = blockIdx.x * 64 + ty * 16;
  const int c  = blockIdx.y * 64 + tx;
  const float* s = src + (HEAD ? 0 : (size_t)a*Ks*N);
  short tmp[16] __attribute__((aligned(16)));
  float bsum = 0.f;
  #pragma unroll
  for (int j = 0; j < 16; j++){
    const int f = f0 + j;
    float w = 0.f;
    if (f < Ks){
      w = HEAD ? s[(((size_t)(c >> 4))*Ks + f)*16 + (c & 15)]
               : s[(size_t)f*N + c];
      if (scale) w *= scale[a*SA + f];
      if (mean)  bsum += mean[a*SA + f] * w;
    }
    tmp[j] = f2bf(w);
  }
  short* d = dst + (size_t)a*aDst + (size_t)c*Kd + f0;
  *(bf16x8v*)d       = *(bf16x8v*)tmp;
  *(bf16x8v*)(d + 8) = *(bf16x8v*)(tmp + 8);
  if (mean){
    __shared__ float red[4][64];
    red[ty][tx] = bsum;
    __syncthreads();
    if (threadIdx.x < 64){
      float t = red[0][threadIdx.x] + red[1][threadIdx.x]
              + red[2][threadIdx.x] + red[3][threadIdx.x];
      atomicAdd(&bias_out[a*biasStride + blockIdx.y*64 + threadIdx.x], -t);
    }
  }
}

// ---------------- MFMA GEMM (linear LDS + global_load_lds + XOR swizzle) ----
// C[a*Bb+row][col] = act( A[row][0..K) @ W'[col][0..K)^T + bias )
// W' layout: [col][K] bf16 (k-contiguous), per-agent stride wPerAgent elems.
// ASRC: 2 bf16 pitch AP; 3 bf16 concat A1(pitch AP)|A2(pitch 256), split at 256.
// MODE: 0 normal (bias[a*biasStride+gc], ACT); 1 kv-split: gc<256 raw,
//       gc>=256 -> + bias[gc-256], lrelu.
// Bank-conflict fix (rule #21, both-sides): LDS stays linear [row][32 shorts];
// the 16B slot within each 64B row is XOR-swizzled by ((row>>1)&3) on BOTH the
// pre-swizzled global source (staging) and the ds_read address (fragments).
// Result: a quarter-wave's 16 b128 reads cover all 32 banks exactly 2x (free).
template<int BM,int BN,int WM,int WN,int K,int ASRC,int AP,bool ACT,bool OUTF32,int MODE>
__global__ __launch_bounds__(256) void mgemm2(const void* A1, const void* A2,
                                              const short* __restrict__ Wp, int wPerAgent,
                                              const float* __restrict__ bias, int biasStride,
                                              void* Out, int outPitch){
  __shared__ __align__(16) short As[BM*32];
  __shared__ __align__(16) short Bs[BN*32];
  const int tid  = threadIdx.x;
  const int a    = blockIdx.z;
  const int row0 = blockIdx.x * BM;
  const int col0 = blockIdx.y * BN;
  const short* Wb = Wp + (size_t)a * wPerAgent;
  constexpr int FM = BM/WM/16, FN = BN/WN/16;
  const int wid = tid >> 6, lane = tid & 63;
  const int wm = wid % WM, wn = wid / WM;
  const int rowB = wm*(BM/WM), colB = wn*(BN/WN);
  const int lrow = lane & 15, lq = lane >> 4;
  const int srow = lane >> 2;                    // staging: row within 16-row block
  const int skc  = ((lane & 3) ^ ((srow >> 1) & 3)) * 8;   // swizzled k-offset (shorts)
  const int rq   = lq ^ ((lrow >> 1) & 3);       // swizzled read slot

  f32x4v acc[FM][FN];
  #pragma unroll
  for (int i = 0; i < FM; i++)
    #pragma unroll
    for (int j = 0; j < FN; j++) acc[i][j] = (f32x4v){0.f,0.f,0.f,0.f};

  constexpr int AB = BM/16;   // 16-row staging blocks for A
  constexpr int BB = BN/16;   // for B

  for (int k0 = 0; k0 < K; k0 += 32){
    // ---- stage A tile (BM x 32) via global_load_lds, 1KB per wave-call ----
    #pragma unroll
    for (int t = 0; t < AB/4; t++){
      const int bb = wid + t*4;                 // wave-uniform block index
      const int r  = bb*16 + srow;
      const int f  = k0 + skc;                  // stays within [k0,k0+32)
      const short* src;
      if constexpr (ASRC == 3)
        src = (f < 256) ? (const short*)A1 + ((size_t)a*Bb + row0 + r)*(size_t)AP + f
                        : (const short*)A2 + ((size_t)a*Bb + row0 + r)*256 + (f - 256);
      else
        src = (const short*)A1 + ((size_t)a*Bb + row0 + r)*(size_t)AP + f;
      gload16(src, &As[bb*512]);
    }
    // ---- stage B tile (BN x 32) from W'[col][k] ----
    #pragma unroll
    for (int t = 0; t < BB/4; t++){
      const int bb = wid + t*4;
      const int r  = bb*16 + srow;
      const short* src = Wb + (size_t)(col0 + r)*K + k0 + skc;
      gload16(src, &Bs[bb*512]);
    }
    __syncthreads();                            // compiler drains vmcnt here
    // ---- fragments + MFMA (swizzled read slot) ----
    bf16x8v af[FM], bfr[FN];
    #pragma unroll
    for (int mi = 0; mi < FM; mi++)
      af[mi] = *(const bf16x8v*)&As[(rowB + mi*16 + lrow)*32 + rq*8];
    #pragma unroll
    for (int ni = 0; ni < FN; ni++)
      bfr[ni] = *(const bf16x8v*)&Bs[(colB + ni*16 + lrow)*32 + rq*8];
    #pragma unroll
    for (int mi = 0; mi < FM; mi++)
      #pragma unroll
      for (int ni = 0; ni < FN; ni++)
        acc[mi][ni] = __builtin_amdgcn_mfma_f32_16x16x32_bf16(af[mi], bfr[ni], acc[mi][ni], 0, 0, 0);
    __syncthreads();
  }
  // ---- epilogue: C/D layout col=lane&15, row=quad*4+reg (m89/m91) ----
  #pragma unroll
  for (int mi = 0; mi < FM; mi++){
    const size_t gr = (size_t)a*Bb + row0 + rowB + mi*16 + lq*4;
    #pragma unroll
    for (int ni = 0; ni < FN; ni++){
      const int gc = col0 + colB + ni*16 + lrow;
      float bb; bool doact;
      if constexpr (MODE == 1){
        doact = (gc >= 256);
        bb = doact ? bias[gc - 256] : 0.f;
      } else {
        bb = bias ? bias[a*biasStride + gc] : 0.f;
        doact = ACT;
      }
      #pragma unroll
      for (int r = 0; r < 4; r++){
        float v = acc[mi][ni][r] + bb;
        if (doact) v = lrelu(v);
        if constexpr (OUTF32) ((float*)Out)[(gr + r)*(size_t)outPitch + gc] = v;
        else                  ((bf16*) Out)[(gr + r)*(size_t)outPitch + gc] = __float2bfloat16(v);
      }
    }
  }
}

// ---------------- attention: KV[row][512] (keys|vals), SEL in place ---------
union B8g { uint4 u; bf16 h[8]; };
__global__ __launch_bounds__(256) void attn_g(const bf16* __restrict__ KV,
                                              bf16* SO){
  const int t = blockIdx.x * 256 + threadIdx.x;   // (b*16 + e)
  const int e = t & 15;
  const size_t b = t >> 4;
  const size_t ofsKV = b*512 + e*16;
  const size_t ofsS  = b*256 + e*16;
  float S[4][16], Kf[4][16], Vf[4][16];
  #pragma unroll
  for (int i = 0; i < 4; i++){
    B8g u0, u1;
    const bf16* sp = SO + (size_t)i*Bb*256 + ofsS;
    u0.u = *(const uint4*)sp; u1.u = *(const uint4*)(sp + 8);
    #pragma unroll
    for (int l = 0; l < 8; l++){ S[i][l] = bf2f(u0.h[l]); S[i][8+l] = bf2f(u1.h[l]); }
    const bf16* kp = KV + (size_t)i*Bb*512 + ofsKV;
    u0.u = *(const uint4*)kp; u1.u = *(const uint4*)(kp + 8);
    #pragma unroll
    for (int l = 0; l < 8; l++){ Kf[i][l] = bf2f(u0.h[l]); Kf[i][8+l] = bf2f(u1.h[l]); }
    const bf16* vp = kp + 256;
    u0.u = *(const uint4*)vp; u1.u = *(const uint4*)(vp + 8);
    #pragma unroll
    for (int l = 0; l < 8; l++){ Vf[i][l] = bf2f(u0.h[l]); Vf[i][8+l] = bf2f(u1.h[l]); }
  }
  #pragma unroll
  for (int i = 0; i < 4; i++){
    float lg[4];
    #pragma unroll
    for (int j = 0; j < 4; j++){
      float d = 0.f;
      #pragma unroll
      for (int l = 0; l < 16; l++) d += S[i][l] * Kf[j][l];
      lg[j] = d * 0.25f;                 // / sqrt(16)
    }
    lg[i] = -1e9f;
    float m = fmaxf(fmaxf(lg[0], lg[1]), fmaxf(lg[2], lg[3]));
    float p[4], s = 0.f;
    #pragma unroll
    for (int j = 0; j < 4; j++){ p[j] = expf(lg[j] - m); s += p[j]; }
    p[i] = 0.f;
    const float inv = 1.f / s;
    float o[16] = {};
    #pragma unroll
    for (int j = 0; j < 4; j++){
      const float pj = p[j] * inv;
      #pragma unroll
      for (int l = 0; l < 16; l++) o[l] += pj * Vf[j][l];
    }
    B8g w0, w1;
    #pragma unroll
    for (int l = 0; l < 8; l++){ w0.h[l] = __float2bfloat16(o[l]); w1.h[l] = __float2bfloat16(o[8+l]); }
    bf16* op = SO + (size_t)i*Bb*256 + ofsS;
    *(uint4*)op       = w0.u;
    *(uint4*)(op + 8) = w1.u;
  }
}

// ---------------- argmax(actions) gather ------------------------------------
__global__ __launch_bounds__(256) void sel_q(const float* __restrict__ actions,
                                             const float* __restrict__ allq,
                                             float* __restrict__ out){
  const size_t i = (size_t)blockIdx.x * 256 + threadIdx.x;  // row = a*Bb + b
  const float* ap = actions + i*64;
  float best = ap[0]; int bi = 0;
  for (int j = 1; j < 64; j++){
    float v = ap[j];
    if (v > best){ best = v; bi = j; }   // first max, matches jnp.argmax
  }
  out[i] = allq[i*64 + bi];
}

// ================= fallback (round-5 verified fused pipeline) ================
constexpr int RB = 4;

template<int K>
__device__ __forceinline__ void gemm4_glb(const float* __restrict__ st,
                                          const float* __restrict__ ac,
                                          const float* __restrict__ mean,
                                          const float* __restrict__ rstd,
                                          int a, int brow0, int tid,
                                          const float* __restrict__ W,
                                          const float* __restrict__ bias, bool act,
                                          float (*Xs)[68], float (*Wt)[264],
                                          float (*Sout)[256]){
  const int r = tid >> 6, c4 = (tid & 63) * 4;
  float acc[4] = {};
  for (int k0 = 0; k0 < K; k0 += 8){
    if (tid < 32){
      const int rb = tid >> 3, kq = tid & 7;
      const int f = k0 + kq;
      float v = (f < Ss) ? st[((size_t)a*Bb + brow0 + rb)*Ss + f]
                         : ac[((size_t)a*Bb + brow0 + rb)*Av + (f - Ss)];
      Xs[kq][rb] = (v - mean[a*SA + f]) * rstd[a*SA + f];
    }
    {
      const int wk = tid >> 5, wc = (tid & 31) * 8;
      const float* wp = W + (size_t)(k0 + wk) * 256 + wc;
      *(float4*)&Wt[wk][wc]     = *(const float4*)wp;
      *(float4*)&Wt[wk][wc + 4] = *(const float4*)(wp + 4);
    }
    __syncthreads();
    #pragma unroll
    for (int kk = 0; kk < 8; kk++){
      const float av = Xs[kk][r];
      float4 w = *(const float4*)&Wt[kk][c4];
      acc[0] += av*w.x; acc[1] += av*w.y; acc[2] += av*w.z; acc[3] += av*w.w;
    }
    __syncthreads();
  }
  float4 o;
  o.x = acc[0] + (bias ? bias[c4+0] : 0.f);
  o.y = acc[1] + (bias ? bias[c4+1] : 0.f);
  o.z = acc[2] + (bias ? bias[c4+2] : 0.f);
  o.w = acc[3] + (bias ? bias[c4+3] : 0.f);
  if (act){ o.x = lrelu(o.x); o.y = lrelu(o.y); o.z = lrelu(o.z); o.w = lrelu(o.w); }
  *(float4*)&Sout[a*RB + r][c4] = o;
}

template<int K, bool HEAD>
__device__ __forceinline__ void gemm4_lds(const float (*S1)[256], const float (*S2)[256],
                                          int a, int tid,
                                          const float* __restrict__ W,
                                          const float* __restrict__ bias, bool act,
                                          float (*Wt)[264], float (*Sout)[256]){
  const int r = tid >> 6, c4 = (tid & 63) * 4;
  float acc[4] = {};
  for (int k0 = 0; k0 < K; k0 += 8){
    if (HEAD){
      const int wk = tid >> 5, c8 = (tid & 31) * 8;
      const int e = c8 >> 4, d0 = c8 & 15;
      const float* wp = W + (size_t)e*(256*16) + (size_t)(k0 + wk)*16 + d0;
      *(float4*)&Wt[wk][c8]     = *(const float4*)wp;
      *(float4*)&Wt[wk][c8 + 4] = *(const float4*)(wp + 4);
    } else {
      const int wk = tid >> 5, wc = (tid & 31) * 8;
      const float* wp = W + (size_t)(k0 + wk)*256 + wc;
      *(float4*)&Wt[wk][wc]     = *(const float4*)wp;
      *(float4*)&Wt[wk][wc + 4] = *(const float4*)(wp + 4);
    }
    __syncthreads();
    const float (*src)[256] = (k0 < 256) ? S1 : S2;
    const int kb = (k0 < 256) ? k0 : k0 - 256;
    const float* arow = &src[a*RB + r][kb];
    #pragma unroll
    for (int kk = 0; kk < 8; kk++){
      const float av = arow[kk];
      float4 w = *(const float4*)&Wt[kk][c4];
      acc[0] += av*w.x; acc[1] += av*w.y; acc[2] += av*w.z; acc[3] += av*w.w;
    }
    __syncthreads();
  }
  float4 o;
  o.x = acc[0] + (bias ? bias[c4+0] : 0.f);
  o.y = acc[1] + (bias ? bias[c4+1] : 0.f);
  o.z = acc[2] + (bias ? bias[c4+2] : 0.f);
  o.w = acc[3] + (bias ? bias[c4+3] : 0.f);
  if (act){ o.x = lrelu(o.x); o.y = lrelu(o.y); o.z = lrelu(o.z); o.w = lrelu(o.w); }
  *(float4*)&Sout[a*RB + r][c4] = o;
}

__global__ __launch_bounds__(256) void fused(
    const float* __restrict__ states, const float* __restrict__ actions,
    const float* __restrict__ mean,  const float* __restrict__ rstd,
    const float* __restrict__ Wenc, const float* __restrict__ benc,
    const float* __restrict__ Wsx,  const float* __restrict__ bsx,
    const float* __restrict__ Wk,   const float* __restrict__ Wsel,
    const float* __restrict__ Wv,   const float* __restrict__ bv,
    const float* __restrict__ Wc1,  const float* __restrict__ bc1,
    const float* __restrict__ Wc2,  const float* __restrict__ bc2,
    float* __restrict__ qout){
  __shared__ float A [16][256];
  __shared__ float Bs2[16][256];
  __shared__ float C [16][256];
  __shared__ float Wt[8][264];
  __shared__ float Xs[8][68];
  __shared__ float Cq[4][68];
  const int tid   = threadIdx.x;
  const int brow0 = blockIdx.x * RB;
  for (int a = 0; a < Nn; a++)
    gemm4_glb<Ss>(states, actions, mean, rstd, a, brow0, tid,
                  Wsx + (size_t)a*Ss*256, bsx + a*256, true, Xs, Wt, A);
  __syncthreads();
  for (int a = 0; a < Nn; a++)
    gemm4_lds<256, true>(A, nullptr, a, tid, Wsel, nullptr, false, Wt, C);
  __syncthreads();
  for (int a = 0; a < Nn; a++)
    gemm4_glb<SA>(states, actions, mean, rstd, a, brow0, tid,
                  Wenc + (size_t)a*SA*256, benc + a*256, true, Xs, Wt, A);
  __syncthreads();
  for (int a = 0; a < Nn; a++)
    gemm4_lds<256, true>(A, nullptr, a, tid, Wk, nullptr, false, Wt, Bs2);
  __syncthreads();
  for (int a = 0; a < Nn; a++)
    gemm4_lds<256, true>(A, nullptr, a, tid, Wv, bv, true, Wt, A);
  __syncthreads();
  if (tid < 64){
    const int rb = tid >> 4, e = tid & 15;
    const int co = e * 16;
    float S[4][16], Kf[4][16], Vf[4][16];
    #pragma unroll
    for (int i = 0; i < 4; i++)
      #pragma unroll
      for (int l = 0; l < 16; l++){
        S[i][l]  = C  [i*RB + rb][co + l];
        Kf[i][l] = Bs2[i*RB + rb][co + l];
        Vf[i][l] = A  [i*RB + rb][co + l];
      }
    #pragma unroll
    for (int i = 0; i < 4; i++){
      float lg[4];
      #pragma unroll
      for (int j = 0; j < 4; j++){
        float d = 0.f;
        #pragma unroll
        for (int l = 0; l < 16; l++) d += S[i][l] * Kf[j][l];
        lg[j] = d * 0.25f;
      }
      lg[i] = -1e9f;
      float m = fmaxf(fmaxf(lg[0], lg[1]), fmaxf(lg[2], lg[3]));
      float p[4], s = 0.f;
      #pragma unroll
      for (int j = 0; j < 4; j++){ p[j] = expf(lg[j] - m); s += p[j]; }
      p[i] = 0.f;
      const float inv = 1.f / s;
      float o[16] = {};
      #pragma unroll
      for (int j = 0; j < 4; j++){
        const float pj = p[j] * inv;
        #pragma unroll
        for (int l = 0; l < 16; l++) o[l] += pj * Vf[j][l];
      }
      #pragma unroll
      for (int l = 0; l < 16; l++) C[i*RB + rb][co + l] = o[l];
    }
  }
  __syncthreads();
  for (int a = 0; a < Nn; a++)
    gemm4_glb<Ss>(states, actions, mean, rstd, a, brow0, tid,
                  Wsx + (size_t)a*Ss*256, bsx + a*256, true, Xs, Wt, A);
  __syncthreads();
  for (int a = 0; a < Nn; a++)
    gemm4_lds<512, false>(A, C, a, tid, Wc1 + (size_t)a*512*256, bc1 + a*256, true, Wt, Bs2);
  __syncthreads();
  for (int a = 0; a < Nn; a++){
    const int r2 = tid >> 6, c2 = tid & 63;
    float acc = 0.f;
    for (int k0 = 0; k0 < 256; k0 += 8){
      const int wk = tid >> 5, wc = (tid & 31) * 2;
      const float* wp = Wc2 + (size_t)a*256*64 + (size_t)(k0 + wk)*64 + wc;
      Wt[wk][wc]     = wp[0];
      Wt[wk][wc + 1] = wp[1];
      __syncthreads();
      #pragma unroll
      for (int kk = 0; kk < 8; kk++) acc += Bs2[a*RB + r2][k0 + kk] * Wt[kk][c2];
      __syncthreads();
    }
    Cq[r2][c2] = acc + bc2[a*64 + c2];
    __syncthreads();
    if (tid < RB){
      const float* ap = actions + ((size_t)a*Bb + brow0 + tid)*Av;
      float best = ap[0]; int bi = 0;
      for (int j = 1; j < Av; j++){
        float v = ap[j];
        if (v > best){ best = v; bi = j; }
      }
      qout[(size_t)a*Bb + brow0 + tid] = Cq[tid][bi];
    }
    __syncthreads();
  }
}

// ================= host =====================================================
extern "C" void kernel_launch(void* const* d_in, const int* in_sizes, int n_in,
                              void* d_out, int out_size, void* d_ws, size_t ws_size,
                              hipStream_t stream){
  (void)in_sizes; (void)n_in; (void)out_size;
  const float* states  = (const float*)d_in[0];
  const float* actions = (const float*)d_in[1];
  const float* Wenc    = (const float*)d_in[2];
  const float* benc    = (const float*)d_in[3];
  const float* Wsx     = (const float*)d_in[4];
  const float* bsx     = (const float*)d_in[5];
  const float* Wk      = (const float*)d_in[6];
  const float* Wsel    = (const float*)d_in[7];
  const float* Wv      = (const float*)d_in[8];
  const float* bv      = (const float*)d_in[9];
  const float* Wc1     = (const float*)d_in[10];
  const float* bc1     = (const float*)d_in[11];
  const float* Wc2     = (const float*)d_in[12];
  const float* bc2     = (const float*)d_in[13];
  float* qout = (float*)d_out;

  char* base = (char*)d_ws;
  float* ssum = (float*)base;                 // 2304 f
  float* ssq  = ssum + Nn*SA;
  float* mean = ssq  + Nn*SA;
  float* rstd = mean + Nn*SA;
  size_t off = 4*Nn*SA*sizeof(float);         // 36864
  float* besc  = (float*)(base + off); off += Nn*512*sizeof(float);      // 8192
  short* Wes_p = (short*)(base + off); off += (size_t)Nn*512*SA*2;       // 2359296
  short* Wkv_p = (short*)(base + off); off += 512*256*2;                 // 262144
  short* Whs_p = (short*)(base + off); off += 256*256*2;                 // 131072
  short* Wc1_p = (short*)(base + off); off += (size_t)Nn*256*512*2;      // 1048576
  short* Wc2_p = (short*)(base + off); off += (size_t)Nn*64*256*2;       // 131072
  const size_t XBFB = (size_t)Nn*Bb*SA*2;     // 150,994,944 B
  const size_t W512 = (size_t)Nn*Bb*512*2;    // 134,217,728 B
  short* Xbf = (short*)(base + off);          // live: conv_stats .. ES GEMM
  bf16*  SEL = (bf16*)(base + off);           // carved from Xbf (born after ES)
  float* ALLQ= (float*)(base + off);          // carved from Xbf (born after c1)
  off += XBFB;
  bf16* ES = (bf16*)(base + off); off += W512;  // [row][512]: sa_enc | s_enc
  bf16* KV = (bf16*)(base + off); off += W512;  // [row][512]: keys | vals; later h
  bf16* H  = KV;                                // h reuses KV (dead after attn)
  const size_t need = off;

  hipMemsetAsync(ssum, 0, 2*Nn*SA*sizeof(float), stream);

  if (ws_size >= need){
    // single pass over fp32 inputs: bf16 convert + BN stats
    conv_stats<true><<<dim3(3, 64, Nn), dim3(64, 4), 0, stream>>>(states, actions, ssum, ssq, Xbf);
    bn_finalize<<<dim3(9), dim3(256), 0, stream>>>(ssum, ssq, mean, rstd);

    // combined bias init, then weight prep
    bias_copy<<<dim3(8), 256, 0, stream>>>(benc, bsx, besc);
    // Wes = [Wenc(cols 0-255, K=576) | Ws zero-padded to K=576 (cols 256-511)]
    foldT2<0><<<dim3(9, 4, Nn), 256, 0, stream>>>(Wenc, rstd, mean, besc,       Wes_p,            SA, SA, 256, 512*SA, 512);
    foldT2<0><<<dim3(9, 4, Nn), 256, 0, stream>>>(Wsx,  rstd, mean, besc + 256, Wes_p + 256*SA,   Ss, SA, 256, 512*SA, 512);
    // Wkv = [Wk(cols 0-255) | Wv(cols 256-511)], shared across agents
    foldT2<1><<<dim3(4, 4, 1), 256, 0, stream>>>(Wk,   nullptr, nullptr, nullptr, Wkv_p,           256, 256, 256, 0, 0);
    foldT2<1><<<dim3(4, 4, 1), 256, 0, stream>>>(Wv,   nullptr, nullptr, nullptr, Wkv_p + 256*256, 256, 256, 256, 0, 0);
    foldT2<1><<<dim3(4, 4, 1), 256, 0, stream>>>(Wsel, nullptr, nullptr, nullptr, Whs_p,           256, 256, 256, 0, 0);
    foldT2<0><<<dim3(8, 4, Nn), 256, 0, stream>>>(Wc1, nullptr, nullptr, nullptr, Wc1_p,           512, 512, 256, 256*512, 0);
    foldT2<0><<<dim3(4, 1, Nn), 256, 0, stream>>>(Wc2, nullptr, nullptr, nullptr, Wc2_p,           256, 256, 64,  64*256,  0);

    // ES = [sa_enc | s_enc] : K=576 GEMM, gy=2 col-tiles (A read twice, bf16)
    mgemm2<64,256,1,4,576,2,SA,true,false,0><<<dim3(Bb/64, 2, Nn), 256, 0, stream>>>(
        Xbf, nullptr, Wes_p, 512*SA, besc, 512, ES, 512);
    // ---- Xbf dead; SEL lives at its base from here ----
    // KV = [keys | vals] : one GEMM over sa_enc (ES cols 0-255), split epilogue
    mgemm2<64,256,1,4,256,2,512,false,false,1><<<dim3(Bb/64, 2, Nn), 256, 0, stream>>>(
        ES, nullptr, Wkv_p, 0, bv, 0, KV, 512);
    // SEL = s_enc @ Wsel  (A = ES cols 256-511)
    mgemm2<64,256,1,4,256,2,512,false,false,0><<<dim3(Bb/64, 1, Nn), 256, 0, stream>>>(
        (const short*)ES + 256, nullptr, Whs_p, 0, nullptr, 0, SEL, 256);
    // SEL = other (in place)
    attn_g<<<dim3(Bb*16/256), 256, 0, stream>>>(KV, SEL);
    // H = lrelu([s_enc | other] @ Wc1 + bc1)  (KV dead -> reuse)
    mgemm2<64,256,1,4,512,3,512,true,false,0><<<dim3(Bb/64, 1, Nn), 256, 0, stream>>>(
        (const short*)ES + 256, SEL, Wc1_p, 256*512, bc1, 256, H, 256);
    // ALLQ = h @ Wc2 + bc2 (fp32)  (SEL dead -> reuse Xbf base)
    mgemm2<64,64,1,4,256,2,256,false,true,0><<<dim3(Bb/64, 1, Nn), 256, 0, stream>>>(
        H, nullptr, Wc2_p, 64*256, bc2, 64, ALLQ, 64);
    // gather argmax
    sel_q<<<dim3(Nn*Bb/256), 256, 0, stream>>>(actions, ALLQ, qout);
  } else {
    // verified fallback (stats-only pass; no Xbf write)
    conv_stats<false><<<dim3(3, 64, Nn), dim3(64, 4), 0, stream>>>(states, actions, ssum, ssq, nullptr);
    bn_finalize<<<dim3(9), dim3(256), 0, stream>>>(ssum, ssq, mean, rstd);
    fused<<<dim3(Bb/RB), 256, 0, stream>>>(states, actions, mean, rstd,
                                           Wenc, benc, Wsx, bsx,
                                           Wk, Wsel, Wv, bv,
                                           Wc1, bc1, Wc2, bc2, qout);
  }
}

// Round 6
// 866.413 us; speedup vs baseline: 1.4138x; 1.0497x over previous
//
#include <hip/hip_runtime.h>
#include <hip/hip_bf16.h>
#include <cstdint>
#include <cstddef>

using bf16 = __hip_bfloat16;
typedef __attribute__((ext_vector_type(8))) short bf16x8v;
typedef __attribute__((ext_vector_type(4))) short bf16x4v;
typedef __attribute__((ext_vector_type(4))) float f32x4v;

constexpr int Nn = 4;       // agents
constexpr int Bb = 32768;   // batch
constexpr int Ss = 512;     // state dim
constexpr int Av = 64;      // action dim
constexpr int SA = 576;     // S + A
constexpr float BN_EPS = 1e-5f;

__device__ __forceinline__ float lrelu(float v){ return v >= 0.f ? v : 0.01f * v; }
__device__ __forceinline__ float bf2f(bf16 x){ return __bfloat162float(x); }
__device__ __forceinline__ short f2bf(float v){
  union { bf16 b; short s; } u; u.b = __float2bfloat16(v); return u.s;
}

// async global->LDS, 16B per lane; LDS dest must be wave-uniform base (HW adds lane*16)
__device__ __forceinline__ void gload16(const void* g, void* l){
  __builtin_amdgcn_global_load_lds(
      (const __attribute__((address_space(1))) unsigned int*)g,
      (__attribute__((address_space(3))) unsigned int*)l, 16, 0, 0);
}

// ---------------- fused convert + BatchNorm statistics ----------------------
template<bool WRX>
__global__ __launch_bounds__(256) void conv_stats(const float* __restrict__ states,
                                                  const float* __restrict__ actions,
                                                  float* __restrict__ ssum,
                                                  float* __restrict__ ssq,
                                                  short* __restrict__ Xbf){
  const int n  = blockIdx.z;
  const int tx = threadIdx.x;
  const int ty = threadIdx.y;
  const int g  = blockIdx.x * 64 + tx;   // feature group of 4
  const bool on = g < (SA / 4);
  const int f  = g * 4;
  const float* p = nullptr; int step = 0;
  if (on){
    if (f < Ss){ p = states  + (size_t)n*Bb*Ss + f;        step = Ss; }
    else       { p = actions + (size_t)n*Bb*Av + (f - Ss); step = Av; }
  }
  float s0=0.f,s1=0.f,s2=0.f,s3=0.f,q0=0.f,q1=0.f,q2=0.f,q3=0.f;
  const int b0 = blockIdx.y * 512 + ty, bend = blockIdx.y * 512 + 512;
  if (on){
    for (int b = b0; b < bend; b += 4){
      float4 v = *(const float4*)(p + (size_t)b*step);
      if (WRX){
        short t4[4] __attribute__((aligned(8))) =
            { f2bf(v.x), f2bf(v.y), f2bf(v.z), f2bf(v.w) };
        *(bf16x4v*)&Xbf[((size_t)n*Bb + b)*SA + f] = *(bf16x4v*)t4;
      }
      s0 += v.x; q0 += v.x*v.x;
      s1 += v.y; q1 += v.y*v.y;
      s2 += v.z; q2 += v.z*v.z;
      s3 += v.w; q3 += v.w*v.w;
    }
  }
  __shared__ float rs[4][64][4], rq[4][64][4];
  rs[ty][tx][0]=s0; rs[ty][tx][1]=s1; rs[ty][tx][2]=s2; rs[ty][tx][3]=s3;
  rq[ty][tx][0]=q0; rq[ty][tx][1]=q1; rq[ty][tx][2]=q2; rq[ty][tx][3]=q3;
  __syncthreads();
  if (ty == 0 && on){
    #pragma unroll
    for (int j = 0; j < 4; j++){
      float ts = rs[0][tx][j]+rs[1][tx][j]+rs[2][tx][j]+rs[3][tx][j];
      float tq = rq[0][tx][j]+rq[1][tx][j]+rq[2][tx][j]+rq[3][tx][j];
      atomicAdd(&ssum[n*SA + f + j], ts);
      atomicAdd(&ssq [n*SA + f + j], tq);
    }
  }
}

__global__ void bn_finalize(const float* __restrict__ ssum, const float* __restrict__ ssq,
                            float* __restrict__ mean, float* __restrict__ rstd){
  int i = blockIdx.x * 256 + threadIdx.x;
  float m = ssum[i] * (1.f / Bb);
  float v = ssq[i] * (1.f / Bb) - m * m;
  v = fmaxf(v, 0.f);
  mean[i] = m;
  rstd[i] = rsqrtf(v + BN_EPS);
}

// ---------------- bias pre-init: besc[a][512] = [benc | bsx] ----------------
__global__ void bias_copy(const float* __restrict__ benc, const float* __restrict__ bsx,
                          float* __restrict__ besc){
  int i = blockIdx.x * 256 + threadIdx.x;
  if (i < Nn*512){
    int a = i >> 9, c = i & 511;
    besc[i] = (c < 256) ? benc[a*256 + c] : bsx[a*256 + (c - 256)];
  }
}

// ---------------- weight prep: transpose to [col][Kd] bf16, optional fold ---
template<int HEAD>
__global__ __launch_bounds__(256) void foldT2(const float* __restrict__ src,
                                              const float* __restrict__ scale,
                                              const float* __restrict__ mean,
                                              float* __restrict__ bias_out,
                                              short* __restrict__ dst,
                                              int Ks, int Kd, int N,
                                              int aDst, int biasStride){
  const int a  = blockIdx.z;
  const int tx = threadIdx.x & 63;
  const int ty = threadIdx.x >> 6;
  const int f0 = blockIdx.x * 64 + ty * 16;
  const int c  = blockIdx.y * 64 + tx;
  const float* s = src + (HEAD ? 0 : (size_t)a*Ks*N);
  short tmp[16] __attribute__((aligned(16)));
  float bsum = 0.f;
  #pragma unroll
  for (int j = 0; j < 16; j++){
    const int f = f0 + j;
    float w = 0.f;
    if (f < Ks){
      w = HEAD ? s[(((size_t)(c >> 4))*Ks + f)*16 + (c & 15)]
               : s[(size_t)f*N + c];
      if (scale) w *= scale[a*SA + f];
      if (mean)  bsum += mean[a*SA + f] * w;
    }
    tmp[j] = f2bf(w);
  }
  short* d = dst + (size_t)a*aDst + (size_t)c*Kd + f0;
  *(bf16x8v*)d       = *(bf16x8v*)tmp;
  *(bf16x8v*)(d + 8) = *(bf16x8v*)(tmp + 8);
  if (mean){
    __shared__ float red[4][64];
    red[ty][tx] = bsum;
    __syncthreads();
    if (threadIdx.x < 64){
      float t = red[0][threadIdx.x] + red[1][threadIdx.x]
              + red[2][threadIdx.x] + red[3][threadIdx.x];
      atomicAdd(&bias_out[a*biasStride + blockIdx.y*64 + threadIdx.x], -t);
    }
  }
}

// ---------------- MFMA GEMM (linear LDS + global_load_lds + XOR swizzle) ----
// C[a*Bb+row][col] = act( A[row][0..K) @ W'[col][0..K)^T + bias )
// W' layout: [col][K] bf16 (k-contiguous), per-agent stride wPerAgent elems.
// ASRC: 2 bf16 pitch AP; 3 bf16 concat A1(pitch AP)|A2(pitch 256), split at 256.
// MODE: 0 normal (bias[a*biasStride+gc], ACT); 1 kv-split: gc<256 raw,
//       gc>=256 -> + bias[gc-256], lrelu.
//       2 allq+argmax-gather: requires BM=64,BN=64,WM=1; A2=actions (fp32),
//         Out=qout (one float per row), bias=bc2.
// Bank-conflict fix (rule #21, both-sides): LDS linear [row][32 shorts]; 16B
// slot XOR-swizzled by ((row>>1)&3) on BOTH pre-swizzled global source and
// ds_read address. Verified: SQ_LDS_BANK_CONFLICT == 0 (round 5).
template<int BM,int BN,int WM,int WN,int K,int ASRC,int AP,bool ACT,bool OUTF32,int MODE>
__global__ __launch_bounds__(256) void mgemm2(const void* A1, const void* A2,
                                              const short* __restrict__ Wp, int wPerAgent,
                                              const float* __restrict__ bias, int biasStride,
                                              void* Out, int outPitch){
  __shared__ __align__(16) short As[BM*32];
  __shared__ __align__(16) short Bs[BN*32];
  const int tid  = threadIdx.x;
  const int a    = blockIdx.z;
  const int row0 = blockIdx.x * BM;
  const int col0 = blockIdx.y * BN;
  const short* Wb = Wp + (size_t)a * wPerAgent;
  constexpr int FM = BM/WM/16, FN = BN/WN/16;
  const int wid = tid >> 6, lane = tid & 63;
  const int wm = wid % WM, wn = wid / WM;
  const int rowB = wm*(BM/WM), colB = wn*(BN/WN);
  const int lrow = lane & 15, lq = lane >> 4;
  const int srow = lane >> 2;                    // staging: row within 16-row block
  const int skc  = ((lane & 3) ^ ((srow >> 1) & 3)) * 8;   // swizzled k-offset (shorts)
  const int rq   = lq ^ ((lrow >> 1) & 3);       // swizzled read slot

  f32x4v acc[FM][FN];
  #pragma unroll
  for (int i = 0; i < FM; i++)
    #pragma unroll
    for (int j = 0; j < FN; j++) acc[i][j] = (f32x4v){0.f,0.f,0.f,0.f};

  constexpr int AB = BM/16;   // 16-row staging blocks for A
  constexpr int BB = BN/16;   // for B

  for (int k0 = 0; k0 < K; k0 += 32){
    // ---- stage A tile (BM x 32) via global_load_lds, 1KB per wave-call ----
    #pragma unroll
    for (int t = 0; t < AB/4; t++){
      const int bb = wid + t*4;                 // wave-uniform block index
      const int r  = bb*16 + srow;
      const int f  = k0 + skc;                  // stays within [k0,k0+32)
      const short* src;
      if constexpr (ASRC == 3)
        src = (f < 256) ? (const short*)A1 + ((size_t)a*Bb + row0 + r)*(size_t)AP + f
                        : (const short*)A2 + ((size_t)a*Bb + row0 + r)*256 + (f - 256);
      else
        src = (const short*)A1 + ((size_t)a*Bb + row0 + r)*(size_t)AP + f;
      gload16(src, &As[bb*512]);
    }
    // ---- stage B tile (BN x 32) from W'[col][k] ----
    #pragma unroll
    for (int t = 0; t < BB/4; t++){
      const int bb = wid + t*4;
      const int r  = bb*16 + srow;
      const short* src = Wb + (size_t)(col0 + r)*K + k0 + skc;
      gload16(src, &Bs[bb*512]);
    }
    __syncthreads();                            // compiler drains vmcnt here
    // ---- fragments + MFMA (swizzled read slot) ----
    bf16x8v af[FM], bfr[FN];
    #pragma unroll
    for (int mi = 0; mi < FM; mi++)
      af[mi] = *(const bf16x8v*)&As[(rowB + mi*16 + lrow)*32 + rq*8];
    #pragma unroll
    for (int ni = 0; ni < FN; ni++)
      bfr[ni] = *(const bf16x8v*)&Bs[(colB + ni*16 + lrow)*32 + rq*8];
    #pragma unroll
    for (int mi = 0; mi < FM; mi++)
      #pragma unroll
      for (int ni = 0; ni < FN; ni++)
        acc[mi][ni] = __builtin_amdgcn_mfma_f32_16x16x32_bf16(af[mi], bfr[ni], acc[mi][ni], 0, 0, 0);
    __syncthreads();
  }
  if constexpr (MODE == 2){
    // ---- fused allq + argmax(actions) gather (BM=64,BN=64,WM=1,FN=1) ----
    __shared__ float Q[64][65];
    #pragma unroll
    for (int mi = 0; mi < FM; mi++){
      const int qr = rowB + mi*16 + lq*4;
      const int gc = colB + lrow;
      const float bb = bias[a*biasStride + col0 + gc];
      #pragma unroll
      for (int r = 0; r < 4; r++)
        Q[qr + r][gc] = acc[mi][0][r] + bb;
    }
    __syncthreads();
    const int row = tid >> 2, seg = (tid & 3) * 16;
    const float* ap = (const float*)A2 + ((size_t)a*Bb + row0 + row)*64 + seg;
    float best = ap[0]; int bi = 0;
    #pragma unroll
    for (int j = 1; j < 16; j++){
      float v = ap[j];
      if (v > best){ best = v; bi = j; }        // first max within segment
    }
    bi += seg;
    #pragma unroll
    for (int d = 1; d < 4; d <<= 1){            // merge 4 lanes; tie -> lower idx
      float ov = __shfl_xor(best, d);
      int   oi = __shfl_xor(bi, d);
      if (ov > best || (ov == best && oi < bi)){ best = ov; bi = oi; }
    }
    if ((tid & 3) == 0)
      ((float*)Out)[(size_t)a*Bb + row0 + row] = Q[row][bi];
  } else {
    // ---- epilogue: C/D layout col=lane&15, row=quad*4+reg (m89/m91) ----
    #pragma unroll
    for (int mi = 0; mi < FM; mi++){
      const size_t gr = (size_t)a*Bb + row0 + rowB + mi*16 + lq*4;
      #pragma unroll
      for (int ni = 0; ni < FN; ni++){
        const int gc = col0 + colB + ni*16 + lrow;
        float bb; bool doact;
        if constexpr (MODE == 1){
          doact = (gc >= 256);
          bb = doact ? bias[gc - 256] : 0.f;
        } else {
          bb = bias ? bias[a*biasStride + gc] : 0.f;
          doact = ACT;
        }
        #pragma unroll
        for (int r = 0; r < 4; r++){
          float v = acc[mi][ni][r] + bb;
          if (doact) v = lrelu(v);
          if constexpr (OUTF32) ((float*)Out)[(gr + r)*(size_t)outPitch + gc] = v;
          else                  ((bf16*) Out)[(gr + r)*(size_t)outPitch + gc] = __float2bfloat16(v);
        }
      }
    }
  }
}

// ---------------- attention: KV[row][512] (keys|vals), SEL in place ---------
union B8g { uint4 u; bf16 h[8]; };
__global__ __launch_bounds__(256) void attn_g(const bf16* __restrict__ KV,
                                              bf16* SO){
  const int t = blockIdx.x * 256 + threadIdx.x;   // (b*16 + e)
  const int e = t & 15;
  const size_t b = t >> 4;
  const size_t ofsKV = b*512 + e*16;
  const size_t ofsS  = b*256 + e*16;
  float S[4][16], Kf[4][16], Vf[4][16];
  #pragma unroll
  for (int i = 0; i < 4; i++){
    B8g u0, u1;
    const bf16* sp = SO + (size_t)i*Bb*256 + ofsS;
    u0.u = *(const uint4*)sp; u1.u = *(const uint4*)(sp + 8);
    #pragma unroll
    for (int l = 0; l < 8; l++){ S[i][l] = bf2f(u0.h[l]); S[i][8+l] = bf2f(u1.h[l]); }
    const bf16* kp = KV + (size_t)i*Bb*512 + ofsKV;
    u0.u = *(const uint4*)kp; u1.u = *(const uint4*)(kp + 8);
    #pragma unroll
    for (int l = 0; l < 8; l++){ Kf[i][l] = bf2f(u0.h[l]); Kf[i][8+l] = bf2f(u1.h[l]); }
    const bf16* vp = kp + 256;
    u0.u = *(const uint4*)vp; u1.u = *(const uint4*)(vp + 8);
    #pragma unroll
    for (int l = 0; l < 8; l++){ Vf[i][l] = bf2f(u0.h[l]); Vf[i][8+l] = bf2f(u1.h[l]); }
  }
  #pragma unroll
  for (int i = 0; i < 4; i++){
    float lg[4];
    #pragma unroll
    for (int j = 0; j < 4; j++){
      float d = 0.f;
      #pragma unroll
      for (int l = 0; l < 16; l++) d += S[i][l] * Kf[j][l];
      lg[j] = d * 0.25f;                 // / sqrt(16)
    }
    lg[i] = -1e9f;
    float m = fmaxf(fmaxf(lg[0], lg[1]), fmaxf(lg[2], lg[3]));
    float p[4], s = 0.f;
    #pragma unroll
    for (int j = 0; j < 4; j++){ p[j] = expf(lg[j] - m); s += p[j]; }
    p[i] = 0.f;
    const float inv = 1.f / s;
    float o[16] = {};
    #pragma unroll
    for (int j = 0; j < 4; j++){
      const float pj = p[j] * inv;
      #pragma unroll
      for (int l = 0; l < 16; l++) o[l] += pj * Vf[j][l];
    }
    B8g w0, w1;
    #pragma unroll
    for (int l = 0; l < 8; l++){ w0.h[l] = __float2bfloat16(o[l]); w1.h[l] = __float2bfloat16(o[8+l]); }
    bf16* op = SO + (size_t)i*Bb*256 + ofsS;
    *(uint4*)op       = w0.u;
    *(uint4*)(op + 8) = w1.u;
  }
}

// ================= fallback (round-5 verified fused pipeline) ================
constexpr int RB = 4;

template<int K>
__device__ __forceinline__ void gemm4_glb(const float* __restrict__ st,
                                          const float* __restrict__ ac,
                                          const float* __restrict__ mean,
                                          const float* __restrict__ rstd,
                                          int a, int brow0, int tid,
                                          const float* __restrict__ W,
                                          const float* __restrict__ bias, bool act,
                                          float (*Xs)[68], float (*Wt)[264],
                                          float (*Sout)[256]){
  const int r = tid >> 6, c4 = (tid & 63) * 4;
  float acc[4] = {};
  for (int k0 = 0; k0 < K; k0 += 8){
    if (tid < 32){
      const int rb = tid >> 3, kq = tid & 7;
      const int f = k0 + kq;
      float v = (f < Ss) ? st[((size_t)a*Bb + brow0 + rb)*Ss + f]
                         : ac[((size_t)a*Bb + brow0 + rb)*Av + (f - Ss)];
      Xs[kq][rb] = (v - mean[a*SA + f]) * rstd[a*SA + f];
    }
    {
      const int wk = tid >> 5, wc = (tid & 31) * 8;
      const float* wp = W + (size_t)(k0 + wk) * 256 + wc;
      *(float4*)&Wt[wk][wc]     = *(const float4*)wp;
      *(float4*)&Wt[wk][wc + 4] = *(const float4*)(wp + 4);
    }
    __syncthreads();
    #pragma unroll
    for (int kk = 0; kk < 8; kk++){
      const float av = Xs[kk][r];
      float4 w = *(const float4*)&Wt[kk][c4];
      acc[0] += av*w.x; acc[1] += av*w.y; acc[2] += av*w.z; acc[3] += av*w.w;
    }
    __syncthreads();
  }
  float4 o;
  o.x = acc[0] + (bias ? bias[c4+0] : 0.f);
  o.y = acc[1] + (bias ? bias[c4+1] : 0.f);
  o.z = acc[2] + (bias ? bias[c4+2] : 0.f);
  o.w = acc[3] + (bias ? bias[c4+3] : 0.f);
  if (act){ o.x = lrelu(o.x); o.y = lrelu(o.y); o.z = lrelu(o.z); o.w = lrelu(o.w); }
  *(float4*)&Sout[a*RB + r][c4] = o;
}

template<int K, bool HEAD>
__device__ __forceinline__ void gemm4_lds(const float (*S1)[256], const float (*S2)[256],
                                          int a, int tid,
                                          const float* __restrict__ W,
                                          const float* __restrict__ bias, bool act,
                                          float (*Wt)[264], float (*Sout)[256]){
  const int r = tid >> 6, c4 = (tid & 63) * 4;
  float acc[4] = {};
  for (int k0 = 0; k0 < K; k0 += 8){
    if (HEAD){
      const int wk = tid >> 5, c8 = (tid & 31) * 8;
      const int e = c8 >> 4, d0 = c8 & 15;
      const float* wp = W + (size_t)e*(256*16) + (size_t)(k0 + wk)*16 + d0;
      *(float4*)&Wt[wk][c8]     = *(const float4*)wp;
      *(float4*)&Wt[wk][c8 + 4] = *(const float4*)(wp + 4);
    } else {
      const int wk = tid >> 5, wc = (tid & 31) * 8;
      const float* wp = W + (size_t)(k0 + wk)*256 + wc;
      *(float4*)&Wt[wk][wc]     = *(const float4*)wp;
      *(float4*)&Wt[wk][wc + 4] = *(const float4*)(wp + 4);
    }
    __syncthreads();
    const float (*src)[256] = (k0 < 256) ? S1 : S2;
    const int kb = (k0 < 256) ? k0 : k0 - 256;
    const float* arow = &src[a*RB + r][kb];
    #pragma unroll
    for (int kk = 0; kk < 8; kk++){
      const float av = arow[kk];
      float4 w = *(const float4*)&Wt[kk][c4];
      acc[0] += av*w.x; acc[1] += av*w.y; acc[2] += av*w.z; acc[3] += av*w.w;
    }
    __syncthreads();
  }
  float4 o;
  o.x = acc[0] + (bias ? bias[c4+0] : 0.f);
  o.y = acc[1] + (bias ? bias[c4+1] : 0.f);
  o.z = acc[2] + (bias ? bias[c4+2] : 0.f);
  o.w = acc[3] + (bias ? bias[c4+3] : 0.f);
  if (act){ o.x = lrelu(o.x); o.y = lrelu(o.y); o.z = lrelu(o.z); o.w = lrelu(o.w); }
  *(float4*)&Sout[a*RB + r][c4] = o;
}

__global__ __launch_bounds__(256) void fused(
    const float* __restrict__ states, const float* __restrict__ actions,
    const float* __restrict__ mean,  const float* __restrict__ rstd,
    const float* __restrict__ Wenc, const float* __restrict__ benc,
    const float* __restrict__ Wsx,  const float* __restrict__ bsx,
    const float* __restrict__ Wk,   const float* __restrict__ Wsel,
    const float* __restrict__ Wv,   const float* __restrict__ bv,
    const float* __restrict__ Wc1,  const float* __restrict__ bc1,
    const float* __restrict__ Wc2,  const float* __restrict__ bc2,
    float* __restrict__ qout){
  __shared__ float A [16][256];
  __shared__ float Bs2[16][256];
  __shared__ float C [16][256];
  __shared__ float Wt[8][264];
  __shared__ float Xs[8][68];
  __shared__ float Cq[4][68];
  const int tid   = threadIdx.x;
  const int brow0 = blockIdx.x * RB;
  for (int a = 0; a < Nn; a++)
    gemm4_glb<Ss>(states, actions, mean, rstd, a, brow0, tid,
                  Wsx + (size_t)a*Ss*256, bsx + a*256, true, Xs, Wt, A);
  __syncthreads();
  for (int a = 0; a < Nn; a++)
    gemm4_lds<256, true>(A, nullptr, a, tid, Wsel, nullptr, false, Wt, C);
  __syncthreads();
  for (int a = 0; a < Nn; a++)
    gemm4_glb<SA>(states, actions, mean, rstd, a, brow0, tid,
                  Wenc + (size_t)a*SA*256, benc + a*256, true, Xs, Wt, A);
  __syncthreads();
  for (int a = 0; a < Nn; a++)
    gemm4_lds<256, true>(A, nullptr, a, tid, Wk, nullptr, false, Wt, Bs2);
  __syncthreads();
  for (int a = 0; a < Nn; a++)
    gemm4_lds<256, true>(A, nullptr, a, tid, Wv, bv, true, Wt, A);
  __syncthreads();
  if (tid < 64){
    const int rb = tid >> 4, e = tid & 15;
    const int co = e * 16;
    float S[4][16], Kf[4][16], Vf[4][16];
    #pragma unroll
    for (int i = 0; i < 4; i++)
      #pragma unroll
      for (int l = 0; l < 16; l++){
        S[i][l]  = C  [i*RB + rb][co + l];
        Kf[i][l] = Bs2[i*RB + rb][co + l];
        Vf[i][l] = A  [i*RB + rb][co + l];
      }
    #pragma unroll
    for (int i = 0; i < 4; i++){
      float lg[4];
      #pragma unroll
      for (int j = 0; j < 4; j++){
        float d = 0.f;
        #pragma unroll
        for (int l = 0; l < 16; l++) d += S[i][l] * Kf[j][l];
        lg[j] = d * 0.25f;
      }
      lg[i] = -1e9f;
      float m = fmaxf(fmaxf(lg[0], lg[1]), fmaxf(lg[2], lg[3]));
      float p[4], s = 0.f;
      #pragma unroll
      for (int j = 0; j < 4; j++){ p[j] = expf(lg[j] - m); s += p[j]; }
      p[i] = 0.f;
      const float inv = 1.f / s;
      float o[16] = {};
      #pragma unroll
      for (int j = 0; j < 4; j++){
        const float pj = p[j] * inv;
        #pragma unroll
        for (int l = 0; l < 16; l++) o[l] += pj * Vf[j][l];
      }
      #pragma unroll
      for (int l = 0; l < 16; l++) C[i*RB + rb][co + l] = o[l];
    }
  }
  __syncthreads();
  for (int a = 0; a < Nn; a++)
    gemm4_glb<Ss>(states, actions, mean, rstd, a, brow0, tid,
                  Wsx + (size_t)a*Ss*256, bsx + a*256, true, Xs, Wt, A);
  __syncthreads();
  for (int a = 0; a < Nn; a++)
    gemm4_lds<512, false>(A, C, a, tid, Wc1 + (size_t)a*512*256, bc1 + a*256, true, Wt, Bs2);
  __syncthreads();
  for (int a = 0; a < Nn; a++){
    const int r2 = tid >> 6, c2 = tid & 63;
    float acc = 0.f;
    for (int k0 = 0; k0 < 256; k0 += 8){
      const int wk = tid >> 5, wc = (tid & 31) * 2;
      const float* wp = Wc2 + (size_t)a*256*64 + (size_t)(k0 + wk)*64 + wc;
      Wt[wk][wc]     = wp[0];
      Wt[wk][wc + 1] = wp[1];
      __syncthreads();
      #pragma unroll
      for (int kk = 0; kk < 8; kk++) acc += Bs2[a*RB + r2][k0 + kk] * Wt[kk][c2];
      __syncthreads();
    }
    Cq[r2][c2] = acc + bc2[a*64 + c2];
    __syncthreads();
    if (tid < RB){
      const float* ap = actions + ((size_t)a*Bb + brow0 + tid)*Av;
      float best = ap[0]; int bi = 0;
      for (int j = 1; j < Av; j++){
        float v = ap[j];
        if (v > best){ best = v; bi = j; }
      }
      qout[(size_t)a*Bb + brow0 + tid] = Cq[tid][bi];
    }
    __syncthreads();
  }
}

// ================= host =====================================================
extern "C" void kernel_launch(void* const* d_in, const int* in_sizes, int n_in,
                              void* d_out, int out_size, void* d_ws, size_t ws_size,
                              hipStream_t stream){
  (void)in_sizes; (void)n_in; (void)out_size;
  const float* states  = (const float*)d_in[0];
  const float* actions = (const float*)d_in[1];
  const float* Wenc    = (const float*)d_in[2];
  const float* benc    = (const float*)d_in[3];
  const float* Wsx     = (const float*)d_in[4];
  const float* bsx     = (const float*)d_in[5];
  const float* Wk      = (const float*)d_in[6];
  const float* Wsel    = (const float*)d_in[7];
  const float* Wv      = (const float*)d_in[8];
  const float* bv      = (const float*)d_in[9];
  const float* Wc1     = (const float*)d_in[10];
  const float* bc1     = (const float*)d_in[11];
  const float* Wc2     = (const float*)d_in[12];
  const float* bc2     = (const float*)d_in[13];
  float* qout = (float*)d_out;

  char* base = (char*)d_ws;
  float* ssum = (float*)base;                 // 2304 f
  float* ssq  = ssum + Nn*SA;
  float* mean = ssq  + Nn*SA;
  float* rstd = mean + Nn*SA;
  size_t off = 4*Nn*SA*sizeof(float);         // 36864
  float* besc  = (float*)(base + off); off += Nn*512*sizeof(float);      // 8192
  short* Wes_p = (short*)(base + off); off += (size_t)Nn*512*SA*2;       // 2359296
  short* Wkv_p = (short*)(base + off); off += 512*256*2;                 // 262144
  short* Whs_p = (short*)(base + off); off += 256*256*2;                 // 131072
  short* Wc1_p = (short*)(base + off); off += (size_t)Nn*256*512*2;      // 1048576
  short* Wc2_p = (short*)(base + off); off += (size_t)Nn*64*256*2;       // 131072
  const size_t XBFB = (size_t)Nn*Bb*SA*2;     // 150,994,944 B
  const size_t W512 = (size_t)Nn*Bb*512*2;    // 134,217,728 B
  short* Xbf = (short*)(base + off);          // live: conv_stats .. ES GEMM
  bf16*  SEL = (bf16*)(base + off);           // carved from Xbf (born after ES)
  off += XBFB;
  bf16* ES = (bf16*)(base + off); off += W512;  // [row][512]: sa_enc | s_enc
  bf16* KV = (bf16*)(base + off); off += W512;  // [row][512]: keys | vals; later h
  bf16* H  = KV;                                // h reuses KV (dead after attn)
  const size_t need = off;

  hipMemsetAsync(ssum, 0, 2*Nn*SA*sizeof(float), stream);

  if (ws_size >= need){
    // single pass over fp32 inputs: bf16 convert + BN stats
    conv_stats<true><<<dim3(3, 64, Nn), dim3(64, 4), 0, stream>>>(states, actions, ssum, ssq, Xbf);
    bn_finalize<<<dim3(9), dim3(256), 0, stream>>>(ssum, ssq, mean, rstd);

    // combined bias init, then weight prep
    bias_copy<<<dim3(8), 256, 0, stream>>>(benc, bsx, besc);
    // Wes = [Wenc(cols 0-255, K=576) | Ws zero-padded to K=576 (cols 256-511)]
    foldT2<0><<<dim3(9, 4, Nn), 256, 0, stream>>>(Wenc, rstd, mean, besc,       Wes_p,            SA, SA, 256, 512*SA, 512);
    foldT2<0><<<dim3(9, 4, Nn), 256, 0, stream>>>(Wsx,  rstd, mean, besc + 256, Wes_p + 256*SA,   Ss, SA, 256, 512*SA, 512);
    // Wkv = [Wk(cols 0-255) | Wv(cols 256-511)], shared across agents
    foldT2<1><<<dim3(4, 4, 1), 256, 0, stream>>>(Wk,   nullptr, nullptr, nullptr, Wkv_p,           256, 256, 256, 0, 0);
    foldT2<1><<<dim3(4, 4, 1), 256, 0, stream>>>(Wv,   nullptr, nullptr, nullptr, Wkv_p + 256*256, 256, 256, 256, 0, 0);
    foldT2<1><<<dim3(4, 4, 1), 256, 0, stream>>>(Wsel, nullptr, nullptr, nullptr, Whs_p,           256, 256, 256, 0, 0);
    foldT2<0><<<dim3(8, 4, Nn), 256, 0, stream>>>(Wc1, nullptr, nullptr, nullptr, Wc1_p,           512, 512, 256, 256*512, 0);
    foldT2<0><<<dim3(4, 1, Nn), 256, 0, stream>>>(Wc2, nullptr, nullptr, nullptr, Wc2_p,           256, 256, 64,  64*256,  0);

    // ES = [sa_enc | s_enc] : K=576 GEMM, m97 128x128 tile, gy=4 col-tiles
    mgemm2<128,128,2,2,576,2,SA,true,false,0><<<dim3(Bb/128, 4, Nn), 256, 0, stream>>>(
        Xbf, nullptr, Wes_p, 512*SA, besc, 512, ES, 512);
    // ---- Xbf dead; SEL lives at its base from here ----
    // KV = [keys | vals] : GEMM over sa_enc (ES cols 0-255), split epilogue
    mgemm2<128,128,2,2,256,2,512,false,false,1><<<dim3(Bb/128, 4, Nn), 256, 0, stream>>>(
        ES, nullptr, Wkv_p, 0, bv, 0, KV, 512);
    // SEL = s_enc @ Wsel  (A = ES cols 256-511)
    mgemm2<128,128,2,2,256,2,512,false,false,0><<<dim3(Bb/128, 2, Nn), 256, 0, stream>>>(
        (const short*)ES + 256, nullptr, Whs_p, 0, nullptr, 0, SEL, 256);
    // SEL = other (in place)
    attn_g<<<dim3(Bb*16/256), 256, 0, stream>>>(KV, SEL);
    // H = lrelu([s_enc | other] @ Wc1 + bc1)  (KV dead -> reuse)
    mgemm2<128,128,2,2,512,3,512,true,false,0><<<dim3(Bb/128, 2, Nn), 256, 0, stream>>>(
        (const short*)ES + 256, SEL, Wc1_p, 256*512, bc1, 256, H, 256);
    // qout = gather(argmax(actions), h @ Wc2 + bc2) — fused epilogue (MODE 2)
    mgemm2<64,64,1,4,256,2,256,false,false,2><<<dim3(Bb/64, 1, Nn), 256, 0, stream>>>(
        H, actions, Wc2_p, 64*256, bc2, 64, qout, 0);
  } else {
    // verified fallback (stats-only pass; no Xbf write)
    conv_stats<false><<<dim3(3, 64, Nn), dim3(64, 4), 0, stream>>>(states, actions, ssum, ssq, nullptr);
    bn_finalize<<<dim3(9), dim3(256), 0, stream>>>(ssum, ssq, mean, rstd);
    fused<<<dim3(Bb/RB), 256, 0, stream>>>(states, actions, mean, rstd,
                                           Wenc, benc, Wsx, bsx,
                                           Wk, Wsel, Wv, bv,
                                           Wc1, bc1, Wc2, bc2, qout);
  }
}